// Round 3
// baseline (414.636 us; speedup 1.0000x reference)
//
#include <hip/hip_runtime.h>
#include <hip/hip_bf16.h>

constexpr int kN = 4096;
constexpr int kDim = 66;   // U + IN
constexpr int kH = 4;
constexpr int kU = 64;
constexpr float kAlpha = 0.2f;
constexpr float kSlope = 0.01f;
constexpr float kLog2e = 1.44269504f;

typedef _Float16 half8 __attribute__((ext_vector_type(8)));
typedef _Float16 half2t __attribute__((ext_vector_type(2)));
typedef __attribute__((ext_vector_type(4))) float floatx4;

__device__ inline unsigned int fkey(float f){ // monotone float->uint key for atomicMax
  unsigned int u = __float_as_uint(f);
  return (u & 0x80000000u) ? ~u : (u | 0x80000000u);
}
__device__ inline float funkey(unsigned int k){
  unsigned int u = (k & 0x80000000u) ? (k ^ 0x80000000u) : ~k;
  return __uint_as_float(u);
}

// ---------- merged setup: pack adjacency + build fp16 x1/x2 + all B matrices + fmax init ----------
__global__ void setup_k(const int* __restrict__ adj, unsigned long long* __restrict__ packed,
                        const float* __restrict__ in2, const float* __restrict__ hx,
                        _Float16* __restrict__ x1b, _Float16* __restrict__ x2b,
                        const float* __restrict__ m1W, const float* __restrict__ m1a1, const float* __restrict__ m1a2,
                        const float* __restrict__ m1Wo, const float* __restrict__ m1ao1, const float* __restrict__ m1ao2,
                        const float* __restrict__ m2W, const float* __restrict__ m2a1, const float* __restrict__ m2a2,
                        const float* __restrict__ m2Wo, const float* __restrict__ m2ao1, const float* __restrict__ m2ao2,
                        const float* __restrict__ g1W, const float* __restrict__ g1b,
                        const float* __restrict__ g2W, const float* __restrict__ g2b,
                        _Float16* __restrict__ B1t, _Float16* __restrict__ B1t2,
                        _Float16* __restrict__ B2t, _Float16* __restrict__ B2t2,
                        _Float16* __restrict__ Bgt, _Float16* __restrict__ Bft,
                        unsigned int* __restrict__ fmaxbuf){
  int bb = blockIdx.x, t = threadIdx.x;
  if (bb < 16384){
    int gid = bb * 256 + t;
    unsigned long long m = __ballot(adj[gid] != 0);
    if ((t & 63) == 0) packed[gid >> 6] = m;
    return;
  }
  if (bb < 16384 + 1024){
    int i = (bb - 16384) * 4 + (t >> 6);
    int c = t & 63;
    x1b[(size_t)i * 96 + 2 + c] = (_Float16)hx[(size_t)i * kU + c];
    if (c < 2){
      _Float16 xv = (_Float16)in2[i * 2 + c];
      x1b[(size_t)i * 96 + c] = xv;
      x2b[(size_t)i * 96 + c] = xv;
    }
    if (c < 30){ // zero pad cols 66..95 (harness poisons ws)
      x1b[(size_t)i * 96 + 66 + c] = (_Float16)0.f;
      x2b[(size_t)i * 96 + 66 + c] = (_Float16)0.f;
    }
    return;
  }
  int b = bb - (16384 + 1024);
  if (b < 8){
    int m = b & 3;
    const float* W  = (b < 4 ? m1W  : m2W)  + (size_t)m * kDim * kDim;
    const float* a1 = (b < 4 ? m1a1 : m2a1) + m * kDim;
    const float* a2 = (b < 4 ? m1a2 : m2a2) + m * kDim;
    _Float16* Bo = (b < 4 ? B1t : B1t2) + (size_t)m * 80 * 96;
    __shared__ float Ws[kDim * kDim];
    __shared__ float wa1s[kDim], wa2s[kDim];
    for (int z = t; z < kDim * kDim; z += 256) Ws[z] = W[z];
    __syncthreads();
    if (t < kDim){
      float s1 = 0.f, s2 = 0.f;
      for (int d = 0; d < kDim; d++){ float wv = Ws[t * kDim + d]; s1 += wv * a1[d]; s2 += wv * a2[d]; }
      wa1s[t] = s1; wa2s[t] = s2;
    }
    __syncthreads();
    for (int z = t; z < 80 * 96; z += 256){
      int nn = z / 96, k = z % 96;
      float val = 0.f;
      if (k < kDim){
        if (nn < kDim) val = Ws[k * kDim + nn];
        else if (nn == 66) val = wa1s[k];
        else if (nn == 67) val = wa2s[k];
      }
      Bo[z] = (_Float16)val;
    }
  } else if (b < 10){
    const float* Wo  = (b == 8 ? m1Wo  : m2Wo);
    const float* ao1 = (b == 8 ? m1ao1 : m2ao1);
    const float* ao2 = (b == 8 ? m1ao2 : m2ao2);
    _Float16* Bo = (b == 8 ? B2t : B2t2);
    __shared__ float wo1s[264], wo2s[264];
    for (int k = t; k < 264; k += 256){
      float s1 = 0.f, s2 = 0.f;
      for (int d = 0; d < kDim; d++){ float wv = Wo[(size_t)k * kDim + d]; s1 += wv * ao1[d]; s2 += wv * ao2[d]; }
      wo1s[k] = s1; wo2s[k] = s2;
    }
    __syncthreads();
    // K index is padded: k = h*72 + c, real Wout row = h*66 + c (c<66). Pad cols -> 0.
    for (int z = t; z < 80 * 288; z += 256){
      int nn = z / 288, k = z % 288;
      int h = k / 72, c = k - h * 72;
      float val = 0.f;
      if (c < 66){
        int kk = h * 66 + c;
        if (nn < kDim) val = Wo[(size_t)kk * kDim + nn];
        else if (nn == 66) val = wo1s[kk];
        else if (nn == 67) val = wo2s[kk];
      }
      Bo[z] = (_Float16)val;
    }
  } else if (b == 10){
    for (int z = t; z < 128 * 96; z += 256){
      int nn = z / 96, k = z % 96;
      float val = 0.f;
      if (k < kDim) val = g1W[k * 128 + nn];
      else if (k == 66) val = g1b[nn];
      Bgt[z] = (_Float16)val;
    }
  } else {
    if (t < 16) fmaxbuf[t] = 0u; // init max-key slots
    for (int z = t; z < 64 * 96; z += 256){
      int nn = z / 96, k = z % 96;
      float val = 0.f;
      if (k < kDim) val = g2W[k * 64 + nn];
      else if (k == 66) val = g2b[nn];
      Bft[z] = (_Float16)val;
    }
  }
}

// ---------- generic MFMA GEMM (fp16) with fused epilogues ----------
// EPI 0: -> Ht (fp16 transposed rows 0..67, row66=ones), f1,f2 (xlog2e, fp32), fmax atomic
// EPI 1: gate -> u = sigmoid; x2b cols 2..65 = sigmoid*hx (fp16)
// EPI 2: final -> out = u*hx + (1-u)*tanh(acc)
template<int KSTEPS, int NT, int EPI>
__global__ __launch_bounds__(256) void gemm_k(
    const _Float16* __restrict__ A, const _Float16* __restrict__ Bt,
    void* __restrict__ p0, void* __restrict__ p1, void* __restrict__ p2,
    const float* __restrict__ aux, unsigned int* __restrict__ fmaxp)
{
  constexpr int KP = KSTEPS * 32;
  const int m = blockIdx.y;
  const int i0 = blockIdx.x * 64;
  const int t = threadIdx.x;
  const int w = t >> 6, lane = t & 63, q = lane >> 4, n = lane & 15;
  const int arow = i0 + w * 16 + n;
  const _Float16* Ar = A + (size_t)arow * KP;
  const _Float16* Bm = Bt + (size_t)m * (NT * 16) * KP;
  floatx4 acc[NT];
  #pragma unroll
  for (int v = 0; v < NT; v++) acc[v] = (floatx4){0.f, 0.f, 0.f, 0.f};
  #pragma unroll
  for (int ks = 0; ks < KSTEPS; ks++){
    half8 af = *(const half8*)&Ar[ks * 32 + q * 8];
    #pragma unroll
    for (int nt = 0; nt < NT; nt++){
      half8 bf = *(const half8*)&Bm[(size_t)(nt * 16 + n) * KP + ks * 32 + q * 8];
      acc[nt] = __builtin_amdgcn_mfma_f32_16x16x32_f16(af, bf, acc[nt], 0, 0, 0);
    }
  }
  const int ib = i0 + w * 16 + q * 4; // D row base
  if constexpr (EPI == 0){
    _Float16* Ht = (_Float16*)p0 + (size_t)m * 68 * kN;
    float* f1 = (float*)p1 + (size_t)m * kN;
    float* f2 = (float*)p2 + (size_t)m * kN;
    float lm = -3e38f;
    #pragma unroll
    for (int nt = 0; nt < NT; nt++){
      int c = nt * 16 + n;
      if (c < kDim){
        union { _Float16 h[4]; uint2 v; } pk;
        pk.h[0] = (_Float16)acc[nt][0]; pk.h[1] = (_Float16)acc[nt][1];
        pk.h[2] = (_Float16)acc[nt][2]; pk.h[3] = (_Float16)acc[nt][3];
        *(uint2*)&Ht[(size_t)c * kN + ib] = pk.v;
      } else if (c == 66){
        float4 fv; fv.x = acc[nt][0] * kLog2e; fv.y = acc[nt][1] * kLog2e;
        fv.z = acc[nt][2] * kLog2e; fv.w = acc[nt][3] * kLog2e;
        *(float4*)&f1[ib] = fv;
        *(uint2*)&Ht[(size_t)66 * kN + ib] = make_uint2(0x3C003C00u, 0x3C003C00u); // fp16 ones
      } else if (c == 67){
        float4 fv; fv.x = acc[nt][0] * kLog2e; fv.y = acc[nt][1] * kLog2e;
        fv.z = acc[nt][2] * kLog2e; fv.w = acc[nt][3] * kLog2e;
        *(float4*)&f2[ib] = fv;
        lm = fmaxf(fmaxf(fv.x, fv.y), fmaxf(fv.z, fv.w));
        *(uint2*)&Ht[(size_t)67 * kN + ib] = make_uint2(0u, 0u);
      } // c >= 68: no store
    }
    lm = fmaxf(lm, __shfl_xor(lm, 16));
    lm = fmaxf(lm, __shfl_xor(lm, 32));
    if (lane == 3) atomicMax(&fmaxp[m], fkey(lm));
  } else if constexpr (EPI == 1){
    float* u = (float*)p0;
    _Float16* x2b = (_Float16*)p1;
    #pragma unroll
    for (int nt = 0; nt < NT; nt++){
      int c = nt * 16 + n;
      #pragma unroll
      for (int r = 0; r < 4; r++){
        float v = 1.f / (1.f + __expf(-acc[nt][r]));
        if (c < 64) x2b[(size_t)(ib + r) * 96 + 2 + c] = (_Float16)(v * aux[(size_t)(ib + r) * kU + c]);
        else        u[(size_t)(ib + r) * kU + (c - 64)] = v;
      }
    }
  } else {
    float* outp = (float*)p0;
    const float* u = (const float*)p1;
    #pragma unroll
    for (int nt = 0; nt < NT; nt++){
      int c = nt * 16 + n;
      #pragma unroll
      for (int r = 0; r < 4; r++){
        float cc = tanhf(acc[nt][r]);
        float uv = u[(size_t)(ib + r) * kU + c];
        outp[(size_t)(ib + r) * kU + c] = uv * aux[(size_t)(ib + r) * kU + c] + (1.f - uv) * cc;
      }
    }
  }
}

// ---------- MFMA attention (fp16, factorized softmax weights), barrier-free ----------
// p_ij = exp2(lrelu(f1+f2)-S) = max(A1*B1_j, A2*B2_j); col 66 of Ht = ones -> l_i.
// B-operand (Ht fragments) read DIRECTLY from global (L2-resident, 16B contiguous
// per lane) -> no LDS staging, no per-chunk barriers. B1/B2 for the whole j-range
// computed once in the prologue (one __syncthreads in the entire kernel).
template<int JSPLIT>
__global__ __launch_bounds__(256, 4) void attn_mfma_k(
    const _Float16* __restrict__ Ht, const float* __restrict__ f1,
    const float* __restrict__ f2, const unsigned int* __restrict__ fmaxu,
    const unsigned long long* __restrict__ packed,
    _Float16* __restrict__ paccb)
{
  constexpr int JR = kN / JSPLIT;      // j-range per block
  constexpr int NCH = JR / 128;        // 128-j chunks
  const int m = blockIdx.y, js = blockIdx.z;
  const int i0 = blockIdx.x * 64;
  const int t = threadIdx.x;
  const int w = t >> 6, lane = t & 63, q = lane >> 4, n = lane & 15;
  const int i = i0 + w * 16 + n;
  const _Float16* Hg = Ht + (size_t)m * 68 * kN;
  const float* f2m = f2 + (size_t)m * kN;
  const float f1v = f1[(size_t)m * kN + i];   // pre-scaled by log2e
  const float fmx = funkey(fmaxu[m]);
  const float t0 = f1v + fmx;
  const float S = fmaxf(t0, kAlpha * t0);      // >= row max of scaled e
  const float A1f = __builtin_amdgcn_exp2f(t0 - S);
  const float A2f = __builtin_amdgcn_exp2f(kAlpha * t0 - S);
  const half2t a1p = { (_Float16)A1f, (_Float16)A1f };
  const half2t a2p = { (_Float16)A2f, (_Float16)A2f };

  __shared__ __align__(16) _Float16 B1h[JR], B2h[JR];

  const int jbase = js * JR;
  for (int z = t; z < JR; z += 256){
    const float v = f2m[jbase + z] - fmx;
    B1h[z] = (_Float16)__builtin_amdgcn_exp2f(v);
    B2h[z] = (_Float16)__builtin_amdgcn_exp2f(kAlpha * v);
  }
  __syncthreads();   // the only barrier

  // per-lane B-operand row pointers (L2-resident). nt=4 rows 68..79 unused:
  // clamp n>=4 to row 64 (finite garbage accumulates into never-stored lanes).
  const _Float16* Hrow[5];
  #pragma unroll
  for (int nt = 0; nt < 4; nt++) Hrow[nt] = Hg + (size_t)(nt * 16 + n) * kN + jbase;
  Hrow[4] = Hg + (size_t)(64 + (n < 4 ? n : 0)) * kN + jbase;
  const int qo = q * 8;

  const unsigned long long* prow = packed + (size_t)i * 64 + (jbase >> 6);

  floatx4 acc[5];
  #pragma unroll
  for (int v = 0; v < 5; v++) acc[v] = (floatx4){0.f, 0.f, 0.f, 0.f};

  #pragma unroll 1
  for (int ch = 0; ch < NCH; ch++){
    const int j0 = ch * 128;
    const unsigned long long w0 = prow[ch * 2];
    const unsigned long long w1 = prow[ch * 2 + 1];
    #pragma unroll
    for (int ks = 0; ks < 4; ks++){
      const unsigned long long wsel = (ks < 2) ? w0 : w1;
      const unsigned int bits = (unsigned int)((wsel >> ((ks & 1) * 32 + qo)) & 0xffull);
      union { uint4 v; unsigned int u[4]; } b1v, b2v;
      b1v.v = *(const uint4*)&B1h[j0 + ks * 32 + qo];
      b2v.v = *(const uint4*)&B2h[j0 + ks * 32 + qo];
      union { half8 s; unsigned int u[4]; } af;
      #pragma unroll
      for (int e = 0; e < 4; e++){
        half2t x1 = __builtin_bit_cast(half2t, b1v.u[e]);
        half2t x2 = __builtin_bit_cast(half2t, b2v.u[e]);
        half2t m1 = x1 * a1p;
        half2t m2 = x2 * a2p;
        half2t pm = __builtin_elementwise_max(m1, m2);
        unsigned int mm = (((bits >> (2 * e)) & 1u) ? 0x0000FFFFu : 0u)
                        | (((bits >> (2 * e + 1)) & 1u) ? 0xFFFF0000u : 0u);
        af.u[e] = __builtin_bit_cast(unsigned int, pm) & mm;
      }
      #pragma unroll
      for (int nt = 0; nt < 5; nt++){
        const half8 bf = *(const half8*)&Hrow[nt][j0 + ks * 32 + qo];
        acc[nt] = __builtin_amdgcn_mfma_f32_16x16x32_f16(af.s, bf, acc[nt], 0, 0, 0);
      }
    }
  }

  _Float16* pw = paccb + ((size_t)(m * JSPLIT + js) * kN + (i0 + w * 16)) * 80;
  #pragma unroll
  for (int nt = 0; nt < 5; nt++){
    if (nt < 4 || n < 4){ // cols >= 68 are unused
      #pragma unroll
      for (int r = 0; r < 4; r++)
        pw[(q * 4 + r) * 80 + nt * 16 + n] = (_Float16)acc[nt][r];
    }
  }
}

// ---------- combine j-split fp16 partials -> lrelu -> fp16 rows (vectorized) ----------
// 64 rows x 4 lanes per block; uint4 loads from 80-stride pacc rows; uint4 stores.
// Writes 9 chunks (72 cols) per head slice; chunk 8: e2 = ones/0, e3..7 = 0.
template<int JSPLIT>
__global__ void combine_k(const _Float16* __restrict__ paccb, _Float16* __restrict__ outb,
                          int ostride, int headoff, int ones_col){
  const int m = blockIdx.y;
  const int t = threadIdx.x;
  const int ri = t >> 2, cg = t & 3;
  const int lane = t & 63;
  const int i = blockIdx.x * 64 + ri;
  const _Float16* pb = paccb + ((size_t)m * JSPLIT * kN + i) * 80;
  float accv[3][8];
  #pragma unroll
  for (int k = 0; k < 3; k++)
    #pragma unroll
    for (int e = 0; e < 8; e++) accv[k][e] = 0.f;
  #pragma unroll
  for (int s = 0; s < JSPLIT; s++){
    const _Float16* ps = pb + (size_t)s * kN * 80;
    #pragma unroll
    for (int k = 0; k < 3; k++){
      const int c = cg + 4 * k;
      if (c < 9){
        union { uint4 v; _Float16 h[8]; } uu;
        uu.v = *(const uint4*)&ps[c * 8];
        #pragma unroll
        for (int e = 0; e < 8; e++) accv[k][e] += (float)uu.h[e];
      }
    }
  }
  // l = pacc col 66 = chunk 8 elem 2 (owned by cg==0, k==2); broadcast in wave
  float l = accv[2][2];
  l = __shfl(l, lane & ~3, 64);
  const float inv = 1.f / l;
  _Float16* orow = outb + (size_t)i * ostride + m * headoff;
  #pragma unroll
  for (int k = 0; k < 3; k++){
    const int c = cg + 4 * k;
    if (c < 9){
      union { uint4 v; _Float16 h[8]; } uu;
      #pragma unroll
      for (int e = 0; e < 8; e++){
        float v = accv[k][e] * inv;
        v = fmaxf(v, kSlope * v);
        uu.h[e] = (_Float16)v;
      }
      if (c == 8){
        uu.h[2] = (_Float16)(ones_col ? 1.f : 0.f);
        #pragma unroll
        for (int e = 3; e < 8; e++) uu.h[e] = (_Float16)0.f;
      }
      *(uint4*)&orow[c * 8] = uu.v;
    }
  }
}

extern "C" void kernel_launch(void* const* d_in, const int* in_sizes, int n_in,
                              void* d_out, int out_size, void* d_ws, size_t ws_size,
                              hipStream_t stream){
  const float* inputs  = (const float*)d_in[0];
  const float* hx      = (const float*)d_in[1];
  const int*   adj     = (const int*)d_in[2];
  const float* m1_W    = (const float*)d_in[3];
  const float* m1_a1   = (const float*)d_in[4];
  const float* m1_a2   = (const float*)d_in[5];
  const float* m1_Wout = (const float*)d_in[6];
  const float* m1_ao1  = (const float*)d_in[7];
  const float* m1_ao2  = (const float*)d_in[8];
  const float* m2_W    = (const float*)d_in[9];
  const float* m2_a1   = (const float*)d_in[10];
  const float* m2_a2   = (const float*)d_in[11];
  const float* m2_Wout = (const float*)d_in[12];
  const float* m2_ao1  = (const float*)d_in[13];
  const float* m2_ao2  = (const float*)d_in[14];
  const float* g1_W    = (const float*)d_in[15];
  const float* g1_b    = (const float*)d_in[16];
  const float* g2_W    = (const float*)d_in[17];
  const float* g2_b    = (const float*)d_in[18];
  float* out = (float*)d_out;

  char* ws = (char*)d_ws;
  size_t off = 0;
  auto alloc = [&](size_t bytes) -> void* {
    void* p = ws + off;
    off = (off + bytes + 255) & ~(size_t)255;
    return p;
  };
  unsigned long long* packed = (unsigned long long*)alloc((size_t)kN * 64 * 8);
  _Float16* x1b  = (_Float16*)alloc((size_t)kN * 96 * 2);
  _Float16* x2b  = (_Float16*)alloc((size_t)kN * 96 * 2);
  _Float16* Ht   = (_Float16*)alloc((size_t)kH * 68 * kN * 2);
  _Float16* Hto  = (_Float16*)alloc((size_t)68 * kN * 2);
  _Float16* hcatb= (_Float16*)alloc((size_t)kN * 288 * 2);
  _Float16* gb   = (_Float16*)alloc((size_t)kN * 96 * 2);
  _Float16* g2bv = (_Float16*)alloc((size_t)kN * 96 * 2);
  float* f1   = (float*)alloc((size_t)kH * kN * 4);
  float* f2   = (float*)alloc((size_t)kH * kN * 4);
  float* fo1  = (float*)alloc((size_t)kN * 4);
  float* fo2  = (float*)alloc((size_t)kN * 4);
  unsigned int* fmaxbuf = (unsigned int*)alloc(64);
  float* u    = (float*)alloc((size_t)kN * kU * 4);
  _Float16* paccb = (_Float16*)alloc((size_t)16 * kN * 80 * 2);
  _Float16* B1t  = (_Float16*)alloc((size_t)kH * 80 * 96 * 2);
  _Float16* B1t2 = (_Float16*)alloc((size_t)kH * 80 * 96 * 2);
  _Float16* B2t  = (_Float16*)alloc((size_t)80 * 288 * 2);
  _Float16* B2t2 = (_Float16*)alloc((size_t)80 * 288 * 2);
  _Float16* Bgt  = (_Float16*)alloc((size_t)128 * 96 * 2);
  _Float16* Bft  = (_Float16*)alloc((size_t)64 * 96 * 2);
  (void)ws_size; (void)in_sizes; (void)n_in; (void)out_size;

  setup_k<<<16384 + 1024 + 12, 256, 0, stream>>>(adj, packed, inputs, hx, x1b, x2b,
      m1_W, m1_a1, m1_a2, m1_Wout, m1_ao1, m1_ao2,
      m2_W, m2_a1, m2_a2, m2_Wout, m2_ao1, m2_ao2,
      g1_W, g1_b, g2_W, g2_b,
      B1t, B1t2, B2t, B2t2, Bgt, Bft, fmaxbuf);

  // ---- subnet 1 ----
  gemm_k<3, 5, 0><<<dim3(64, kH), 256, 0, stream>>>(x1b, B1t, Ht, f1, f2, nullptr, fmaxbuf + 0);
  attn_mfma_k<4><<<dim3(64, kH, 4), 256, 0, stream>>>(Ht, f1, f2, fmaxbuf + 0, packed, paccb);
  combine_k<4><<<dim3(64, kH), 256, 0, stream>>>(paccb, hcatb, 288, 72, 0);
  gemm_k<9, 5, 0><<<dim3(64, 1), 256, 0, stream>>>(hcatb, B2t, Hto, fo1, fo2, nullptr, fmaxbuf + 4);
  attn_mfma_k<8><<<dim3(64, 1, 8), 256, 0, stream>>>(Hto, fo1, fo2, fmaxbuf + 4, packed, paccb);
  combine_k<8><<<dim3(64, 1), 256, 0, stream>>>(paccb, gb, 96, 0, 1);
  gemm_k<3, 8, 1><<<dim3(64, 1), 256, 0, stream>>>(gb, Bgt, u, x2b, nullptr, hx, nullptr);

  // ---- subnet 2 ----
  gemm_k<3, 5, 0><<<dim3(64, kH), 256, 0, stream>>>(x2b, B1t2, Ht, f1, f2, nullptr, fmaxbuf + 5);
  attn_mfma_k<4><<<dim3(64, kH, 4), 256, 0, stream>>>(Ht, f1, f2, fmaxbuf + 5, packed, paccb);
  combine_k<4><<<dim3(64, kH), 256, 0, stream>>>(paccb, hcatb, 288, 72, 0);
  gemm_k<9, 5, 0><<<dim3(64, 1), 256, 0, stream>>>(hcatb, B2t2, Hto, fo1, fo2, nullptr, fmaxbuf + 9);
  attn_mfma_k<8><<<dim3(64, 1, 8), 256, 0, stream>>>(Hto, fo1, fo2, fmaxbuf + 9, packed, paccb);
  combine_k<8><<<dim3(64, 1), 256, 0, stream>>>(paccb, g2bv, 96, 0, 1);
  gemm_k<3, 4, 2><<<dim3(64, 1), 256, 0, stream>>>(g2bv, Bft, out, u, nullptr, hx, nullptr);
}

// Round 4
// 305.858 us; speedup vs baseline: 1.3556x; 1.3556x over previous
//
#include <hip/hip_runtime.h>
#include <hip/hip_bf16.h>

constexpr int kN = 4096;
constexpr int kDim = 66;   // U + IN
constexpr int kH = 4;
constexpr int kU = 64;
constexpr float kAlpha = 0.2f;
constexpr float kSlope = 0.01f;
constexpr float kLog2e = 1.44269504f;

typedef _Float16 half8 __attribute__((ext_vector_type(8)));
typedef _Float16 half2t __attribute__((ext_vector_type(2)));
typedef __attribute__((ext_vector_type(4))) float floatx4;

__device__ inline unsigned int fkey(float f){ // monotone float->uint key for atomicMax
  unsigned int u = __float_as_uint(f);
  return (u & 0x80000000u) ? ~u : (u | 0x80000000u);
}
__device__ inline float funkey(unsigned int k){
  unsigned int u = (k & 0x80000000u) ? (k ^ 0x80000000u) : ~k;
  return __uint_as_float(u);
}

__device__ __forceinline__ void gld_lds16(const void* g, void* l){
  __builtin_amdgcn_global_load_lds((const __attribute__((address_space(1))) unsigned int*)g,
                                   (__attribute__((address_space(3))) unsigned int*)l, 16, 0, 0);
}

// ---------- merged setup: pack adjacency + build fp16 x1/x2 + all B matrices + fmax init ----------
__global__ void setup_k(const int* __restrict__ adj, unsigned long long* __restrict__ packed,
                        const float* __restrict__ in2, const float* __restrict__ hx,
                        _Float16* __restrict__ x1b, _Float16* __restrict__ x2b,
                        const float* __restrict__ m1W, const float* __restrict__ m1a1, const float* __restrict__ m1a2,
                        const float* __restrict__ m1Wo, const float* __restrict__ m1ao1, const float* __restrict__ m1ao2,
                        const float* __restrict__ m2W, const float* __restrict__ m2a1, const float* __restrict__ m2a2,
                        const float* __restrict__ m2Wo, const float* __restrict__ m2ao1, const float* __restrict__ m2ao2,
                        const float* __restrict__ g1W, const float* __restrict__ g1b,
                        const float* __restrict__ g2W, const float* __restrict__ g2b,
                        _Float16* __restrict__ B1t, _Float16* __restrict__ B1t2,
                        _Float16* __restrict__ B2t, _Float16* __restrict__ B2t2,
                        _Float16* __restrict__ Bgt, _Float16* __restrict__ Bft,
                        unsigned int* __restrict__ fmaxbuf){
  int bb = blockIdx.x, t = threadIdx.x;
  if (bb < 16384){
    int gid = bb * 256 + t;
    unsigned long long m = __ballot(adj[gid] != 0);
    if ((t & 63) == 0) packed[gid >> 6] = m;
    return;
  }
  if (bb < 16384 + 1024){
    int i = (bb - 16384) * 4 + (t >> 6);
    int c = t & 63;
    x1b[(size_t)i * 96 + 2 + c] = (_Float16)hx[(size_t)i * kU + c];
    if (c < 2){
      _Float16 xv = (_Float16)in2[i * 2 + c];
      x1b[(size_t)i * 96 + c] = xv;
      x2b[(size_t)i * 96 + c] = xv;
    }
    if (c < 30){ // zero pad cols 66..95 (harness poisons ws)
      x1b[(size_t)i * 96 + 66 + c] = (_Float16)0.f;
      x2b[(size_t)i * 96 + 66 + c] = (_Float16)0.f;
    }
    return;
  }
  int b = bb - (16384 + 1024);
  if (b < 8){
    int m = b & 3;
    const float* W  = (b < 4 ? m1W  : m2W)  + (size_t)m * kDim * kDim;
    const float* a1 = (b < 4 ? m1a1 : m2a1) + m * kDim;
    const float* a2 = (b < 4 ? m1a2 : m2a2) + m * kDim;
    _Float16* Bo = (b < 4 ? B1t : B1t2) + (size_t)m * 80 * 96;
    __shared__ float Ws[kDim * kDim];
    __shared__ float wa1s[kDim], wa2s[kDim];
    for (int z = t; z < kDim * kDim; z += 256) Ws[z] = W[z];
    __syncthreads();
    if (t < kDim){
      float s1 = 0.f, s2 = 0.f;
      for (int d = 0; d < kDim; d++){ float wv = Ws[t * kDim + d]; s1 += wv * a1[d]; s2 += wv * a2[d]; }
      wa1s[t] = s1; wa2s[t] = s2;
    }
    __syncthreads();
    for (int z = t; z < 80 * 96; z += 256){
      int nn = z / 96, k = z % 96;
      float val = 0.f;
      if (k < kDim){
        if (nn < kDim) val = Ws[k * kDim + nn];
        else if (nn == 66) val = wa1s[k];
        else if (nn == 67) val = wa2s[k];
      }
      Bo[z] = (_Float16)val;
    }
  } else if (b < 10){
    const float* Wo  = (b == 8 ? m1Wo  : m2Wo);
    const float* ao1 = (b == 8 ? m1ao1 : m2ao1);
    const float* ao2 = (b == 8 ? m1ao2 : m2ao2);
    _Float16* Bo = (b == 8 ? B2t : B2t2);
    __shared__ float wo1s[264], wo2s[264];
    for (int k = t; k < 264; k += 256){
      float s1 = 0.f, s2 = 0.f;
      for (int d = 0; d < kDim; d++){ float wv = Wo[(size_t)k * kDim + d]; s1 += wv * ao1[d]; s2 += wv * ao2[d]; }
      wo1s[k] = s1; wo2s[k] = s2;
    }
    __syncthreads();
    // K index is padded: k = h*72 + c, real Wout row = h*66 + c (c<66). Pad cols -> 0.
    for (int z = t; z < 80 * 288; z += 256){
      int nn = z / 288, k = z % 288;
      int h = k / 72, c = k - h * 72;
      float val = 0.f;
      if (c < 66){
        int kk = h * 66 + c;
        if (nn < kDim) val = Wo[(size_t)kk * kDim + nn];
        else if (nn == 66) val = wo1s[kk];
        else if (nn == 67) val = wo2s[kk];
      }
      Bo[z] = (_Float16)val;
    }
  } else if (b == 10){
    for (int z = t; z < 128 * 96; z += 256){
      int nn = z / 96, k = z % 96;
      float val = 0.f;
      if (k < kDim) val = g1W[k * 128 + nn];
      else if (k == 66) val = g1b[nn];
      Bgt[z] = (_Float16)val;
    }
  } else {
    if (t < 16) fmaxbuf[t] = 0u; // init max-key slots
    for (int z = t; z < 64 * 96; z += 256){
      int nn = z / 96, k = z % 96;
      float val = 0.f;
      if (k < kDim) val = g2W[k * 64 + nn];
      else if (k == 66) val = g2b[nn];
      Bft[z] = (_Float16)val;
    }
  }
}

// ---------- generic MFMA GEMM (fp16), 64-thread blocks (16 rows), fused epilogues ----------
// EPI 0: -> Ht (fp16 transposed rows 0..67, row66=ones), f1,f2 (xlog2e, fp32), fmax atomic
// EPI 1: gate -> u = sigmoid; x2b cols 2..65 = sigmoid*hx (fp16)
// EPI 2: final -> out = u*hx + (1-u)*tanh(acc)
template<int KSTEPS, int NT, int EPI>
__global__ __launch_bounds__(64) void gemm_k(
    const _Float16* __restrict__ A, const _Float16* __restrict__ Bt,
    void* __restrict__ p0, void* __restrict__ p1, void* __restrict__ p2,
    const float* __restrict__ aux, unsigned int* __restrict__ fmaxp)
{
  constexpr int KP = KSTEPS * 32;
  const int m = blockIdx.y;
  const int i0 = blockIdx.x * 16;
  const int lane = threadIdx.x;
  const int q = lane >> 4, n = lane & 15;
  const int arow = i0 + n;
  const _Float16* Ar = A + (size_t)arow * KP;
  const _Float16* Bm = Bt + (size_t)m * (NT * 16) * KP;
  floatx4 acc[NT];
  #pragma unroll
  for (int v = 0; v < NT; v++) acc[v] = (floatx4){0.f, 0.f, 0.f, 0.f};
  #pragma unroll
  for (int ks = 0; ks < KSTEPS; ks++){
    half8 af = *(const half8*)&Ar[ks * 32 + q * 8];
    #pragma unroll
    for (int nt = 0; nt < NT; nt++){
      half8 bf = *(const half8*)&Bm[(size_t)(nt * 16 + n) * KP + ks * 32 + q * 8];
      acc[nt] = __builtin_amdgcn_mfma_f32_16x16x32_f16(af, bf, acc[nt], 0, 0, 0);
    }
  }
  const int ib = i0 + q * 4; // D row base
  if constexpr (EPI == 0){
    _Float16* Ht = (_Float16*)p0 + (size_t)m * 68 * kN;
    float* f1 = (float*)p1 + (size_t)m * kN;
    float* f2 = (float*)p2 + (size_t)m * kN;
    float lm = -3e38f;
    #pragma unroll
    for (int nt = 0; nt < NT; nt++){
      int c = nt * 16 + n;
      if (c < kDim){
        union { _Float16 h[4]; uint2 v; } pk;
        pk.h[0] = (_Float16)acc[nt][0]; pk.h[1] = (_Float16)acc[nt][1];
        pk.h[2] = (_Float16)acc[nt][2]; pk.h[3] = (_Float16)acc[nt][3];
        *(uint2*)&Ht[(size_t)c * kN + ib] = pk.v;
      } else if (c == 66){
        float4 fv; fv.x = acc[nt][0] * kLog2e; fv.y = acc[nt][1] * kLog2e;
        fv.z = acc[nt][2] * kLog2e; fv.w = acc[nt][3] * kLog2e;
        *(float4*)&f1[ib] = fv;
        *(uint2*)&Ht[(size_t)66 * kN + ib] = make_uint2(0x3C003C00u, 0x3C003C00u); // fp16 ones
      } else if (c == 67){
        float4 fv; fv.x = acc[nt][0] * kLog2e; fv.y = acc[nt][1] * kLog2e;
        fv.z = acc[nt][2] * kLog2e; fv.w = acc[nt][3] * kLog2e;
        *(float4*)&f2[ib] = fv;
        lm = fmaxf(fmaxf(fv.x, fv.y), fmaxf(fv.z, fv.w));
        *(uint2*)&Ht[(size_t)67 * kN + ib] = make_uint2(0u, 0u);
      } // c >= 68: no store
    }
    lm = fmaxf(lm, __shfl_xor(lm, 16));
    lm = fmaxf(lm, __shfl_xor(lm, 32));
    if (lane == 3) atomicMax(&fmaxp[m], fkey(lm));
  } else if constexpr (EPI == 1){
    float* u = (float*)p0;
    _Float16* x2b = (_Float16*)p1;
    #pragma unroll
    for (int nt = 0; nt < NT; nt++){
      int c = nt * 16 + n;
      #pragma unroll
      for (int r = 0; r < 4; r++){
        float v = 1.f / (1.f + __expf(-acc[nt][r]));
        if (c < 64) x2b[(size_t)(ib + r) * 96 + 2 + c] = (_Float16)(v * aux[(size_t)(ib + r) * kU + c]);
        else        u[(size_t)(ib + r) * kU + (c - 64)] = v;
      }
    }
  } else {
    float* outp = (float*)p0;
    const float* u = (const float*)p1;
    #pragma unroll
    for (int nt = 0; nt < NT; nt++){
      int c = nt * 16 + n;
      #pragma unroll
      for (int r = 0; r < 4; r++){
        float cc = tanhf(acc[nt][r]);
        float uv = u[(size_t)(ib + r) * kU + c];
        outp[(size_t)(ib + r) * kU + c] = uv * aux[(size_t)(ib + r) * kU + c] + (1.f - uv) * cc;
      }
    }
  }
}

// ---------- MFMA attention (fp16, factorized softmax weights) ----------
// Round-1 proven structure: glds double-buffered LDS staging, XOR-swizzled source,
// swizzled ds_read_b128 consume. p_ij = max(A1*B1_j, A2*B2_j); Ht row66=ones -> l_i.
template<int JSPLIT>
__global__ __launch_bounds__(256, 4) void attn_mfma_k(
    const _Float16* __restrict__ Ht, const float* __restrict__ f1,
    const float* __restrict__ f2, const unsigned int* __restrict__ fmaxu,
    const unsigned long long* __restrict__ packed,
    _Float16* __restrict__ paccb)
{
  constexpr int JR = kN / JSPLIT;      // j-range per block
  constexpr int NCH = JR / 128;        // 128-j chunks (even)
  const int m = blockIdx.y, js = blockIdx.z;
  const int i0 = blockIdx.x * 64;
  const int t = threadIdx.x;
  const int w = t >> 6, lane = t & 63, q = lane >> 4, n = lane & 15;
  const int i = i0 + w * 16 + n;
  const _Float16* Hg = Ht + (size_t)m * 68 * kN;
  const float* f2m = f2 + (size_t)m * kN;
  const float f1v = f1[(size_t)m * kN + i];   // pre-scaled by log2e
  const float fmx = funkey(fmaxu[m]);
  const float t0 = f1v + fmx;
  const float S = fmaxf(t0, kAlpha * t0);      // >= row max of scaled e
  const float A1f = __builtin_amdgcn_exp2f(t0 - S);
  const float A2f = __builtin_amdgcn_exp2f(kAlpha * t0 - S);
  const half2t a1p = { (_Float16)A1f, (_Float16)A1f };
  const half2t a2p = { (_Float16)A2f, (_Float16)A2f };

  __shared__ __align__(16) _Float16 buf[2][68 * 128];
  __shared__ __align__(16) _Float16 Zro[128];
  __shared__ __align__(16) _Float16 B1h[2][128], B2h[2][128];

  for (int z = t; z < 128; z += 256) Zro[z] = (_Float16)0.f;

  const int r4 = q;                 // lane>>4 : row-within-64-group
  const int cse = n ^ r4;           // col swizzle, even k (row&7 = r4)
  const int cso = cse ^ 4;          // odd k (row&7 = 4|r4)

  const int jbase = js * JR;
  const unsigned long long* prow = packed + (size_t)i * 64;
  const int jj = (w << 5) | (lane & 31);
  const bool blane = (lane & 32) == 0;

  // glds: 17 calls cover rows 0..67 x 16 uint4; linear LDS dest, XOR-swizzled global src.
#define STAGE_G(PD, CH) do { \
    const _Float16* gB_ = Hg + jbase + (CH) * 128; \
    _Pragma("unroll") \
    for (int kk_ = 0; kk_ < 5; kk_++){ \
      const int k_ = w + kk_ * 4; \
      if (k_ < 17){ \
        const int row_ = k_ * 4 + r4; \
        const int csw_ = (k_ & 1) ? cso : cse; \
        gld_lds16(gB_ + (size_t)row_ * kN + csw_ * 8, &buf[(PD)][k_ * 512]); \
      } \
    } \
  } while (0)

  floatx4 acc[5];
  #pragma unroll
  for (int v = 0; v < 5; v++) acc[v] = (floatx4){0.f, 0.f, 0.f, 0.f};

  // prologue: stage chunk 0 into slot 0
  if (blane){
    const float v_ = f2m[jbase + jj] - fmx;
    B1h[0][jj] = (_Float16)__builtin_amdgcn_exp2f(v_);
    B2h[0][jj] = (_Float16)__builtin_amdgcn_exp2f(kAlpha * v_);
  }
  STAGE_G(0, 0);
  __syncthreads();

  int ch = 0;
#define BODY(P) do { \
    const int j0_ = jbase + ch * 128; \
    float f2v_ = 0.f; \
    const bool doB_ = (ch + 1 < NCH) && blane; \
    if (doB_) f2v_ = f2m[j0_ + 128 + jj]; \
    const unsigned long long w0_ = prow[j0_ >> 6]; \
    const unsigned long long w1_ = prow[(j0_ >> 6) + 1]; \
    __builtin_amdgcn_sched_barrier(0); \
    if (ch + 1 < NCH) STAGE_G((P) ^ 1, ch + 1); \
    __builtin_amdgcn_sched_barrier(0); \
    if (doB_){ \
      const float v_ = f2v_ - fmx; \
      B1h[(P) ^ 1][jj] = (_Float16)__builtin_amdgcn_exp2f(v_); \
      B2h[(P) ^ 1][jj] = (_Float16)__builtin_amdgcn_exp2f(kAlpha * v_); \
    } \
    const _Float16* bz_ = (n < 4) ? &buf[(P)][(64 + n) * 128] : Zro; \
    _Pragma("unroll") \
    for (int ks = 0; ks < 4; ks++){ \
      const unsigned long long wsel = (ks < 2) ? w0_ : w1_; \
      const unsigned int bits = (unsigned int)((wsel >> ((ks & 1) * 32 + q * 8)) & 0xffull); \
      union { uint4 v; unsigned int u[4]; } b1v, b2v; \
      b1v.v = *(const uint4*)&B1h[(P)][ks * 32 + q * 8]; \
      b2v.v = *(const uint4*)&B2h[(P)][ks * 32 + q * 8]; \
      union { half8 s; unsigned int u[4]; } af; \
      _Pragma("unroll") \
      for (int e = 0; e < 4; e++){ \
        half2t x1 = __builtin_bit_cast(half2t, b1v.u[e]); \
        half2t x2 = __builtin_bit_cast(half2t, b2v.u[e]); \
        half2t m1 = x1 * a1p; \
        half2t m2 = x2 * a2p; \
        half2t pm = __builtin_elementwise_max(m1, m2); \
        unsigned int mm = (((bits >> (2 * e)) & 1u) ? 0x0000FFFFu : 0u) \
                        | (((bits >> (2 * e + 1)) & 1u) ? 0xFFFF0000u : 0u); \
        af.u[e] = __builtin_bit_cast(unsigned int, pm) & mm; \
      } \
      const int cs_ = ((ks * 4 + q) ^ (n & 7)) * 8; \
      _Pragma("unroll") \
      for (int nt = 0; nt < 4; nt++){ \
        const half8 bf = *(const half8*)&buf[(P)][(nt * 16 + n) * 128 + cs_]; \
        acc[nt] = __builtin_amdgcn_mfma_f32_16x16x32_f16(af.s, bf, acc[nt], 0, 0, 0); \
      } \
      { const half8 bf4 = *(const half8*)&bz_[cs_]; \
        acc[4] = __builtin_amdgcn_mfma_f32_16x16x32_f16(af.s, bf4, acc[4], 0, 0, 0); } \
    } \
    ch++; \
    if (ch < NCH) __syncthreads(); \
  } while (0)

  #pragma unroll 1
  for (int it = 0; it < NCH / 2; it++){
    BODY(0);
    BODY(1);
  }
#undef BODY
#undef STAGE_G

  _Float16* pw = paccb + ((size_t)(m * JSPLIT + js) * kN + (i0 + w * 16)) * 80;
  #pragma unroll
  for (int nt = 0; nt < 5; nt++){
    if (nt < 4 || n < 4){ // cols >= 68 are unused
      #pragma unroll
      for (int r = 0; r < 4; r++)
        pw[(q * 4 + r) * 80 + nt * 16 + n] = (_Float16)acc[nt][r];
    }
  }
}

// ---------- combine j-split fp16 partials -> lrelu -> fp16 rows (vectorized) ----------
// 32 rows x 8 lanes per block; uint4 loads from 80-stride pacc rows; uint4 stores.
// Lane cg handles chunk cg; cg==0 also handles chunk 8 (cols 64..71 with specials).
template<int JSPLIT>
__global__ __launch_bounds__(256) void combine_k(const _Float16* __restrict__ paccb,
                          _Float16* __restrict__ outb,
                          int ostride, int headoff, int ones_col){
  const int m = blockIdx.y;
  const int t = threadIdx.x;
  const int ri = t >> 3, cg = t & 7;
  const int lane = t & 63;
  const int i = blockIdx.x * 32 + ri;
  const _Float16* pb = paccb + ((size_t)m * JSPLIT * kN + i) * 80;
  float accv[2][8];
  #pragma unroll
  for (int k = 0; k < 2; k++)
    #pragma unroll
    for (int e = 0; e < 8; e++) accv[k][e] = 0.f;
  #pragma unroll
  for (int s = 0; s < JSPLIT; s++){
    const _Float16* ps = pb + (size_t)s * kN * 80;
    union { uint4 v; _Float16 h[8]; } uu;
    uu.v = *(const uint4*)&ps[cg * 8];
    #pragma unroll
    for (int e = 0; e < 8; e++) accv[0][e] += (float)uu.h[e];
    if (cg == 0){
      uu.v = *(const uint4*)&ps[64];
      #pragma unroll
      for (int e = 0; e < 8; e++) accv[1][e] += (float)uu.h[e];
    }
  }
  // l = pacc col 66 = chunk 8 elem 2 (owned by cg==0); broadcast across 8-lane row group
  float l = accv[1][2];
  l = __shfl(l, lane & 56, 64);
  const float inv = 1.f / l;
  _Float16* orow = outb + (size_t)i * ostride + m * headoff;
  {
    union { uint4 v; _Float16 h[8]; } uu;
    #pragma unroll
    for (int e = 0; e < 8; e++){
      float v = accv[0][e] * inv;
      v = fmaxf(v, kSlope * v);
      uu.h[e] = (_Float16)v;
    }
    *(uint4*)&orow[cg * 8] = uu.v;
  }
  if (cg == 0){
    union { uint4 v; _Float16 h[8]; } uu;
    #pragma unroll
    for (int e = 0; e < 2; e++){
      float v = accv[1][e] * inv;
      v = fmaxf(v, kSlope * v);
      uu.h[e] = (_Float16)v;
    }
    uu.h[2] = (_Float16)(ones_col ? 1.f : 0.f);
    #pragma unroll
    for (int e = 3; e < 8; e++) uu.h[e] = (_Float16)0.f;
    *(uint4*)&orow[64] = uu.v;
  }
}

extern "C" void kernel_launch(void* const* d_in, const int* in_sizes, int n_in,
                              void* d_out, int out_size, void* d_ws, size_t ws_size,
                              hipStream_t stream){
  const float* inputs  = (const float*)d_in[0];
  const float* hx      = (const float*)d_in[1];
  const int*   adj     = (const int*)d_in[2];
  const float* m1_W    = (const float*)d_in[3];
  const float* m1_a1   = (const float*)d_in[4];
  const float* m1_a2   = (const float*)d_in[5];
  const float* m1_Wout = (const float*)d_in[6];
  const float* m1_ao1  = (const float*)d_in[7];
  const float* m1_ao2  = (const float*)d_in[8];
  const float* m2_W    = (const float*)d_in[9];
  const float* m2_a1   = (const float*)d_in[10];
  const float* m2_a2   = (const float*)d_in[11];
  const float* m2_Wout = (const float*)d_in[12];
  const float* m2_ao1  = (const float*)d_in[13];
  const float* m2_ao2  = (const float*)d_in[14];
  const float* g1_W    = (const float*)d_in[15];
  const float* g1_b    = (const float*)d_in[16];
  const float* g2_W    = (const float*)d_in[17];
  const float* g2_b    = (const float*)d_in[18];
  float* out = (float*)d_out;

  char* ws = (char*)d_ws;
  size_t off = 0;
  auto alloc = [&](size_t bytes) -> void* {
    void* p = ws + off;
    off = (off + bytes + 255) & ~(size_t)255;
    return p;
  };
  unsigned long long* packed = (unsigned long long*)alloc((size_t)kN * 64 * 8);
  _Float16* x1b  = (_Float16*)alloc((size_t)kN * 96 * 2);
  _Float16* x2b  = (_Float16*)alloc((size_t)kN * 96 * 2);
  _Float16* Ht   = (_Float16*)alloc((size_t)kH * 68 * kN * 2);
  _Float16* Hto  = (_Float16*)alloc((size_t)68 * kN * 2);
  _Float16* hcatb= (_Float16*)alloc((size_t)kN * 288 * 2);
  _Float16* gb   = (_Float16*)alloc((size_t)kN * 96 * 2);
  _Float16* g2bv = (_Float16*)alloc((size_t)kN * 96 * 2);
  float* f1   = (float*)alloc((size_t)kH * kN * 4);
  float* f2   = (float*)alloc((size_t)kH * kN * 4);
  float* fo1  = (float*)alloc((size_t)kN * 4);
  float* fo2  = (float*)alloc((size_t)kN * 4);
  unsigned int* fmaxbuf = (unsigned int*)alloc(64);
  float* u    = (float*)alloc((size_t)kN * kU * 4);
  _Float16* paccb = (_Float16*)alloc((size_t)16 * kN * 80 * 2);
  _Float16* B1t  = (_Float16*)alloc((size_t)kH * 80 * 96 * 2);
  _Float16* B1t2 = (_Float16*)alloc((size_t)kH * 80 * 96 * 2);
  _Float16* B2t  = (_Float16*)alloc((size_t)80 * 288 * 2);
  _Float16* B2t2 = (_Float16*)alloc((size_t)80 * 288 * 2);
  _Float16* Bgt  = (_Float16*)alloc((size_t)128 * 96 * 2);
  _Float16* Bft  = (_Float16*)alloc((size_t)64 * 96 * 2);
  (void)ws_size; (void)in_sizes; (void)n_in; (void)out_size;

  setup_k<<<16384 + 1024 + 12, 256, 0, stream>>>(adj, packed, inputs, hx, x1b, x2b,
      m1_W, m1_a1, m1_a2, m1_Wout, m1_ao1, m1_ao2,
      m2_W, m2_a1, m2_a2, m2_Wout, m2_ao1, m2_ao2,
      g1_W, g1_b, g2_W, g2_b,
      B1t, B1t2, B2t, B2t2, Bgt, Bft, fmaxbuf);

  // ---- subnet 1 ----
  gemm_k<3, 5, 0><<<dim3(256, kH), 64, 0, stream>>>(x1b, B1t, Ht, f1, f2, nullptr, fmaxbuf + 0);
  attn_mfma_k<4><<<dim3(64, kH, 4), 256, 0, stream>>>(Ht, f1, f2, fmaxbuf + 0, packed, paccb);
  combine_k<4><<<dim3(128, kH), 256, 0, stream>>>(paccb, hcatb, 288, 72, 0);
  gemm_k<9, 5, 0><<<dim3(256, 1), 64, 0, stream>>>(hcatb, B2t, Hto, fo1, fo2, nullptr, fmaxbuf + 4);
  attn_mfma_k<16><<<dim3(64, 1, 16), 256, 0, stream>>>(Hto, fo1, fo2, fmaxbuf + 4, packed, paccb);
  combine_k<16><<<dim3(128, 1), 256, 0, stream>>>(paccb, gb, 96, 0, 1);
  gemm_k<3, 8, 1><<<dim3(256, 1), 64, 0, stream>>>(gb, Bgt, u, x2b, nullptr, hx, nullptr);

  // ---- subnet 2 ----
  gemm_k<3, 5, 0><<<dim3(256, kH), 64, 0, stream>>>(x2b, B1t2, Ht, f1, f2, nullptr, fmaxbuf + 5);
  attn_mfma_k<4><<<dim3(64, kH, 4), 256, 0, stream>>>(Ht, f1, f2, fmaxbuf + 5, packed, paccb);
  combine_k<4><<<dim3(128, kH), 256, 0, stream>>>(paccb, hcatb, 288, 72, 0);
  gemm_k<9, 5, 0><<<dim3(256, 1), 64, 0, stream>>>(hcatb, B2t2, Hto, fo1, fo2, nullptr, fmaxbuf + 9);
  attn_mfma_k<16><<<dim3(64, 1, 16), 256, 0, stream>>>(Hto, fo1, fo2, fmaxbuf + 9, packed, paccb);
  combine_k<16><<<dim3(128, 1), 256, 0, stream>>>(paccb, g2bv, 96, 0, 1);
  gemm_k<3, 4, 2><<<dim3(256, 1), 64, 0, stream>>>(g2bv, Bft, out, u, nullptr, hx, nullptr);
}

// Round 5
// 301.242 us; speedup vs baseline: 1.3764x; 1.0153x over previous
//
#include <hip/hip_runtime.h>
#include <hip/hip_bf16.h>

constexpr int kN = 4096;
constexpr int kDim = 66;   // U + IN
constexpr int kH = 4;
constexpr int kU = 64;
constexpr float kAlpha = 0.2f;
constexpr float kSlope = 0.01f;
constexpr float kLog2e = 1.44269504f;

typedef _Float16 half8 __attribute__((ext_vector_type(8)));
typedef _Float16 half2t __attribute__((ext_vector_type(2)));
typedef __attribute__((ext_vector_type(4))) float floatx4;

__device__ inline unsigned int fkey(float f){ // monotone float->uint key for atomicMax
  unsigned int u = __float_as_uint(f);
  return (u & 0x80000000u) ? ~u : (u | 0x80000000u);
}
__device__ inline float funkey(unsigned int k){
  unsigned int u = (k & 0x80000000u) ? (k ^ 0x80000000u) : ~k;
  return __uint_as_float(u);
}

__device__ __forceinline__ void gld_lds16(const void* g, void* l){
  __builtin_amdgcn_global_load_lds((const __attribute__((address_space(1))) unsigned int*)g,
                                   (__attribute__((address_space(3))) unsigned int*)l, 16, 0, 0);
}

// ---------- merged setup: pack adjacency + build fp16 x1/x2 + all B matrices + fmax init ----------
__global__ void setup_k(const int* __restrict__ adj, unsigned long long* __restrict__ packed,
                        const float* __restrict__ in2, const float* __restrict__ hx,
                        _Float16* __restrict__ x1b, _Float16* __restrict__ x2b,
                        const float* __restrict__ m1W, const float* __restrict__ m1a1, const float* __restrict__ m1a2,
                        const float* __restrict__ m1Wo, const float* __restrict__ m1ao1, const float* __restrict__ m1ao2,
                        const float* __restrict__ m2W, const float* __restrict__ m2a1, const float* __restrict__ m2a2,
                        const float* __restrict__ m2Wo, const float* __restrict__ m2ao1, const float* __restrict__ m2ao2,
                        const float* __restrict__ g1W, const float* __restrict__ g1b,
                        const float* __restrict__ g2W, const float* __restrict__ g2b,
                        _Float16* __restrict__ B1t, _Float16* __restrict__ B1t2,
                        _Float16* __restrict__ B2t, _Float16* __restrict__ B2t2,
                        _Float16* __restrict__ Bgt, _Float16* __restrict__ Bft,
                        unsigned int* __restrict__ fmaxbuf){
  int bb = blockIdx.x, t = threadIdx.x;
  if (bb < 16384){
    int gid = bb * 256 + t;
    unsigned long long m = __ballot(adj[gid] != 0);
    if ((t & 63) == 0) packed[gid >> 6] = m;
    return;
  }
  if (bb < 16384 + 1024){
    int i = (bb - 16384) * 4 + (t >> 6);
    int c = t & 63;
    x1b[(size_t)i * 96 + 2 + c] = (_Float16)hx[(size_t)i * kU + c];
    if (c < 2){
      _Float16 xv = (_Float16)in2[i * 2 + c];
      x1b[(size_t)i * 96 + c] = xv;
      x2b[(size_t)i * 96 + c] = xv;
    }
    if (c < 30){ // zero pad cols 66..95 (harness poisons ws)
      x1b[(size_t)i * 96 + 66 + c] = (_Float16)0.f;
      x2b[(size_t)i * 96 + 66 + c] = (_Float16)0.f;
    }
    return;
  }
  int b = bb - (16384 + 1024);
  if (b < 8){
    int m = b & 3;
    const float* W  = (b < 4 ? m1W  : m2W)  + (size_t)m * kDim * kDim;
    const float* a1 = (b < 4 ? m1a1 : m2a1) + m * kDim;
    const float* a2 = (b < 4 ? m1a2 : m2a2) + m * kDim;
    _Float16* Bo = (b < 4 ? B1t : B1t2) + (size_t)m * 80 * 96;
    __shared__ float Ws[kDim * kDim];
    __shared__ float wa1s[kDim], wa2s[kDim];
    for (int z = t; z < kDim * kDim; z += 256) Ws[z] = W[z];
    __syncthreads();
    if (t < kDim){
      float s1 = 0.f, s2 = 0.f;
      for (int d = 0; d < kDim; d++){ float wv = Ws[t * kDim + d]; s1 += wv * a1[d]; s2 += wv * a2[d]; }
      wa1s[t] = s1; wa2s[t] = s2;
    }
    __syncthreads();
    for (int z = t; z < 80 * 96; z += 256){
      int nn = z / 96, k = z % 96;
      float val = 0.f;
      if (k < kDim){
        if (nn < kDim) val = Ws[k * kDim + nn];
        else if (nn == 66) val = wa1s[k];
        else if (nn == 67) val = wa2s[k];
      }
      Bo[z] = (_Float16)val;
    }
  } else if (b < 10){
    const float* Wo  = (b == 8 ? m1Wo  : m2Wo);
    const float* ao1 = (b == 8 ? m1ao1 : m2ao1);
    const float* ao2 = (b == 8 ? m1ao2 : m2ao2);
    _Float16* Bo = (b == 8 ? B2t : B2t2);
    __shared__ float wo1s[264], wo2s[264];
    for (int k = t; k < 264; k += 256){
      float s1 = 0.f, s2 = 0.f;
      for (int d = 0; d < kDim; d++){ float wv = Wo[(size_t)k * kDim + d]; s1 += wv * ao1[d]; s2 += wv * ao2[d]; }
      wo1s[k] = s1; wo2s[k] = s2;
    }
    __syncthreads();
    // 96 B rows (last 16 are zero pad for the slab-split GEMM).
    // K index is padded: k = h*72 + c, real Wout row = h*66 + c (c<66). Pad cols -> 0.
    for (int z = t; z < 96 * 288; z += 256){
      int nn = z / 288, k = z % 288;
      int h = k / 72, c = k - h * 72;
      float val = 0.f;
      if (c < 66 && nn < 80){
        int kk = h * 66 + c;
        if (nn < kDim) val = Wo[(size_t)kk * kDim + nn];
        else if (nn == 66) val = wo1s[kk];
        else if (nn == 67) val = wo2s[kk];
      }
      Bo[(size_t)nn * 288 + k] = (_Float16)val;
    }
  } else if (b == 10){
    for (int z = t; z < 128 * 96; z += 256){
      int nn = z / 96, k = z % 96;
      float val = 0.f;
      if (k < kDim) val = g1W[k * 128 + nn];
      else if (k == 66) val = g1b[nn];
      Bgt[z] = (_Float16)val;
    }
  } else {
    if (t < 16) fmaxbuf[t] = 0u; // init max-key slots
    for (int z = t; z < 64 * 96; z += 256){
      int nn = z / 96, k = z % 96;
      float val = 0.f;
      if (k < kDim) val = g2W[k * 64 + nn];
      else if (k == 66) val = g2b[nn];
      Bft[z] = (_Float16)val;
    }
  }
}

// ---------- generic MFMA GEMM (fp16) with fused epilogues ----------
// blockIdx.y = head (SLAB=0) or column-slab (SLAB=1). B offset is identical in
// both modes (m*NT*16*KP); SLAB only shifts the epilogue column base and drops
// the per-head output offset.
// EPI 0: -> Ht (fp16 transposed rows 0..67, row66=ones), f1,f2 (xlog2e, fp32), fmax atomic
// EPI 1: gate -> u = sigmoid; x2b cols 2..65 = sigmoid*hx (fp16)
// EPI 2: final -> out = u*hx + (1-u)*tanh(acc)
template<int KSTEPS, int NT, int EPI, bool SLAB>
__global__ __launch_bounds__(256) void gemm_k(
    const _Float16* __restrict__ A, const _Float16* __restrict__ Bt,
    void* __restrict__ p0, void* __restrict__ p1, void* __restrict__ p2,
    const float* __restrict__ aux, unsigned int* __restrict__ fmaxp)
{
  constexpr int KP = KSTEPS * 32;
  const int m = blockIdx.y;
  const int i0 = blockIdx.x * 64;
  const int t = threadIdx.x;
  const int w = t >> 6, lane = t & 63, q = lane >> 4, n = lane & 15;
  const int arow = i0 + w * 16 + n;
  const _Float16* Ar = A + (size_t)arow * KP;
  const _Float16* Bm = Bt + (size_t)m * (NT * 16) * KP;
  const int head = SLAB ? 0 : m;
  const int cbase = SLAB ? m * (NT * 16) : 0;
  floatx4 acc[NT];
  #pragma unroll
  for (int v = 0; v < NT; v++) acc[v] = (floatx4){0.f, 0.f, 0.f, 0.f};
  #pragma unroll
  for (int ks = 0; ks < KSTEPS; ks++){
    half8 af = *(const half8*)&Ar[ks * 32 + q * 8];
    #pragma unroll
    for (int nt = 0; nt < NT; nt++){
      half8 bf = *(const half8*)&Bm[(size_t)(nt * 16 + n) * KP + ks * 32 + q * 8];
      acc[nt] = __builtin_amdgcn_mfma_f32_16x16x32_f16(af, bf, acc[nt], 0, 0, 0);
    }
  }
  const int ib = i0 + w * 16 + q * 4; // D row base
  if constexpr (EPI == 0){
    _Float16* Ht = (_Float16*)p0 + (size_t)head * 68 * kN;
    float* f1 = (float*)p1 + (size_t)head * kN;
    float* f2 = (float*)p2 + (size_t)head * kN;
    float lm = -3e38f;
    #pragma unroll
    for (int nt = 0; nt < NT; nt++){
      int c = cbase + nt * 16 + n;
      if (c < kDim){
        union { _Float16 h[4]; uint2 v; } pk;
        pk.h[0] = (_Float16)acc[nt][0]; pk.h[1] = (_Float16)acc[nt][1];
        pk.h[2] = (_Float16)acc[nt][2]; pk.h[3] = (_Float16)acc[nt][3];
        *(uint2*)&Ht[(size_t)c * kN + ib] = pk.v;
      } else if (c == 66){
        float4 fv; fv.x = acc[nt][0] * kLog2e; fv.y = acc[nt][1] * kLog2e;
        fv.z = acc[nt][2] * kLog2e; fv.w = acc[nt][3] * kLog2e;
        *(float4*)&f1[ib] = fv;
        *(uint2*)&Ht[(size_t)66 * kN + ib] = make_uint2(0x3C003C00u, 0x3C003C00u); // fp16 ones
      } else if (c == 67){
        float4 fv; fv.x = acc[nt][0] * kLog2e; fv.y = acc[nt][1] * kLog2e;
        fv.z = acc[nt][2] * kLog2e; fv.w = acc[nt][3] * kLog2e;
        *(float4*)&f2[ib] = fv;
        lm = fmaxf(fmaxf(fv.x, fv.y), fmaxf(fv.z, fv.w));
        *(uint2*)&Ht[(size_t)67 * kN + ib] = make_uint2(0u, 0u);
      } // c >= 68: no store
    }
    lm = fmaxf(lm, __shfl_xor(lm, 16));
    lm = fmaxf(lm, __shfl_xor(lm, 32));
    if (lane == 3) atomicMax(&fmaxp[head], fkey(lm));
  } else if constexpr (EPI == 1){
    float* u = (float*)p0;
    _Float16* x2b = (_Float16*)p1;
    #pragma unroll
    for (int nt = 0; nt < NT; nt++){
      int c = cbase + nt * 16 + n;
      #pragma unroll
      for (int r = 0; r < 4; r++){
        float v = 1.f / (1.f + __expf(-acc[nt][r]));
        if (c < 64) x2b[(size_t)(ib + r) * 96 + 2 + c] = (_Float16)(v * aux[(size_t)(ib + r) * kU + c]);
        else        u[(size_t)(ib + r) * kU + (c - 64)] = v;
      }
    }
  } else {
    float* outp = (float*)p0;
    const float* u = (const float*)p1;
    #pragma unroll
    for (int nt = 0; nt < NT; nt++){
      int c = cbase + nt * 16 + n;
      #pragma unroll
      for (int r = 0; r < 4; r++){
        float cc = tanhf(acc[nt][r]);
        float uv = u[(size_t)(ib + r) * kU + c];
        outp[(size_t)(ib + r) * kU + c] = uv * aux[(size_t)(ib + r) * kU + c] + (1.f - uv) * cc;
      }
    }
  }
}

// ---------- MFMA attention (fp16, factorized softmax weights) ----------
// Round-1 proven structure: glds double-buffered LDS staging, XOR-swizzled source,
// swizzled ds_read_b128 consume. p_ij = max(A1*B1_j, A2*B2_j); Ht row66=ones -> l_i.
template<int JSPLIT>
__global__ __launch_bounds__(256, 4) void attn_mfma_k(
    const _Float16* __restrict__ Ht, const float* __restrict__ f1,
    const float* __restrict__ f2, const unsigned int* __restrict__ fmaxu,
    const unsigned long long* __restrict__ packed,
    _Float16* __restrict__ paccb)
{
  constexpr int JR = kN / JSPLIT;      // j-range per block
  constexpr int NCH = JR / 128;        // 128-j chunks (even)
  const int m = blockIdx.y, js = blockIdx.z;
  const int i0 = blockIdx.x * 64;
  const int t = threadIdx.x;
  const int w = t >> 6, lane = t & 63, q = lane >> 4, n = lane & 15;
  const int i = i0 + w * 16 + n;
  const _Float16* Hg = Ht + (size_t)m * 68 * kN;
  const float* f2m = f2 + (size_t)m * kN;
  const float f1v = f1[(size_t)m * kN + i];   // pre-scaled by log2e
  const float fmx = funkey(fmaxu[m]);
  const float t0 = f1v + fmx;
  const float S = fmaxf(t0, kAlpha * t0);      // >= row max of scaled e
  const float A1f = __builtin_amdgcn_exp2f(t0 - S);
  const float A2f = __builtin_amdgcn_exp2f(kAlpha * t0 - S);
  const half2t a1p = { (_Float16)A1f, (_Float16)A1f };
  const half2t a2p = { (_Float16)A2f, (_Float16)A2f };

  __shared__ __align__(16) _Float16 buf[2][68 * 128];
  __shared__ __align__(16) _Float16 Zro[128];
  __shared__ __align__(16) _Float16 B1h[2][128], B2h[2][128];

  for (int z = t; z < 128; z += 256) Zro[z] = (_Float16)0.f;

  const int r4 = q;                 // lane>>4 : row-within-64-group
  const int cse = n ^ r4;           // col swizzle, even k (row&7 = r4)
  const int cso = cse ^ 4;          // odd k (row&7 = 4|r4)

  const int jbase = js * JR;
  const unsigned long long* prow = packed + (size_t)i * 64;
  const int jj = (w << 5) | (lane & 31);
  const bool blane = (lane & 32) == 0;

  // glds: 17 calls cover rows 0..67 x 16 uint4; linear LDS dest, XOR-swizzled global src.
#define STAGE_G(PD, CH) do { \
    const _Float16* gB_ = Hg + jbase + (CH) * 128; \
    _Pragma("unroll") \
    for (int kk_ = 0; kk_ < 5; kk_++){ \
      const int k_ = w + kk_ * 4; \
      if (k_ < 17){ \
        const int row_ = k_ * 4 + r4; \
        const int csw_ = (k_ & 1) ? cso : cse; \
        gld_lds16(gB_ + (size_t)row_ * kN + csw_ * 8, &buf[(PD)][k_ * 512]); \
      } \
    } \
  } while (0)

  floatx4 acc[5];
  #pragma unroll
  for (int v = 0; v < 5; v++) acc[v] = (floatx4){0.f, 0.f, 0.f, 0.f};

  // prologue: stage chunk 0 into slot 0
  if (blane){
    const float v_ = f2m[jbase + jj] - fmx;
    B1h[0][jj] = (_Float16)__builtin_amdgcn_exp2f(v_);
    B2h[0][jj] = (_Float16)__builtin_amdgcn_exp2f(kAlpha * v_);
  }
  STAGE_G(0, 0);
  __syncthreads();

  int ch = 0;
#define BODY(P) do { \
    const int j0_ = jbase + ch * 128; \
    float f2v_ = 0.f; \
    const bool doB_ = (ch + 1 < NCH) && blane; \
    if (doB_) f2v_ = f2m[j0_ + 128 + jj]; \
    const unsigned long long w0_ = prow[j0_ >> 6]; \
    const unsigned long long w1_ = prow[(j0_ >> 6) + 1]; \
    __builtin_amdgcn_sched_barrier(0); \
    if (ch + 1 < NCH) STAGE_G((P) ^ 1, ch + 1); \
    __builtin_amdgcn_sched_barrier(0); \
    if (doB_){ \
      const float v_ = f2v_ - fmx; \
      B1h[(P) ^ 1][jj] = (_Float16)__builtin_amdgcn_exp2f(v_); \
      B2h[(P) ^ 1][jj] = (_Float16)__builtin_amdgcn_exp2f(kAlpha * v_); \
    } \
    const _Float16* bz_ = (n < 4) ? &buf[(P)][(64 + n) * 128] : Zro; \
    _Pragma("unroll") \
    for (int ks = 0; ks < 4; ks++){ \
      const unsigned long long wsel = (ks < 2) ? w0_ : w1_; \
      const unsigned int bits = (unsigned int)((wsel >> ((ks & 1) * 32 + q * 8)) & 0xffull); \
      union { uint4 v; unsigned int u[4]; } b1v, b2v; \
      b1v.v = *(const uint4*)&B1h[(P)][ks * 32 + q * 8]; \
      b2v.v = *(const uint4*)&B2h[(P)][ks * 32 + q * 8]; \
      union { half8 s; unsigned int u[4]; } af; \
      _Pragma("unroll") \
      for (int e = 0; e < 4; e++){ \
        half2t x1 = __builtin_bit_cast(half2t, b1v.u[e]); \
        half2t x2 = __builtin_bit_cast(half2t, b2v.u[e]); \
        half2t m1 = x1 * a1p; \
        half2t m2 = x2 * a2p; \
        half2t pm = __builtin_elementwise_max(m1, m2); \
        unsigned int mm = (((bits >> (2 * e)) & 1u) ? 0x0000FFFFu : 0u) \
                        | (((bits >> (2 * e + 1)) & 1u) ? 0xFFFF0000u : 0u); \
        af.u[e] = __builtin_bit_cast(unsigned int, pm) & mm; \
      } \
      const int cs_ = ((ks * 4 + q) ^ (n & 7)) * 8; \
      _Pragma("unroll") \
      for (int nt = 0; nt < 4; nt++){ \
        const half8 bf = *(const half8*)&buf[(P)][(nt * 16 + n) * 128 + cs_]; \
        acc[nt] = __builtin_amdgcn_mfma_f32_16x16x32_f16(af.s, bf, acc[nt], 0, 0, 0); \
      } \
      { const half8 bf4 = *(const half8*)&bz_[cs_]; \
        acc[4] = __builtin_amdgcn_mfma_f32_16x16x32_f16(af.s, bf4, acc[4], 0, 0, 0); } \
    } \
    ch++; \
    if (ch < NCH) __syncthreads(); \
  } while (0)

  #pragma unroll 1
  for (int it = 0; it < NCH / 2; it++){
    BODY(0);
    BODY(1);
  }
#undef BODY
#undef STAGE_G

  _Float16* pw = paccb + ((size_t)(m * JSPLIT + js) * kN + (i0 + w * 16)) * 80;
  #pragma unroll
  for (int nt = 0; nt < 5; nt++){
    if (nt < 4 || n < 4){ // cols >= 68 are unused
      #pragma unroll
      for (int r = 0; r < 4; r++)
        pw[(q * 4 + r) * 80 + nt * 16 + n] = (_Float16)acc[nt][r];
    }
  }
}

// ---------- combine j-split fp16 partials -> lrelu -> fp16 rows (vectorized) ----------
// 32 rows x 8 lanes per block; uint4 loads from 80-stride pacc rows; uint4 stores.
// Lane cg handles chunk cg; cg==0 also handles chunk 8 (cols 64..71 with specials).
template<int JSPLIT>
__global__ __launch_bounds__(256) void combine_k(const _Float16* __restrict__ paccb,
                          _Float16* __restrict__ outb,
                          int ostride, int headoff, int ones_col){
  const int m = blockIdx.y;
  const int t = threadIdx.x;
  const int ri = t >> 3, cg = t & 7;
  const int lane = t & 63;
  const int i = blockIdx.x * 32 + ri;
  const _Float16* pb = paccb + ((size_t)m * JSPLIT * kN + i) * 80;
  float accv[2][8];
  #pragma unroll
  for (int k = 0; k < 2; k++)
    #pragma unroll
    for (int e = 0; e < 8; e++) accv[k][e] = 0.f;
  #pragma unroll
  for (int s = 0; s < JSPLIT; s++){
    const _Float16* ps = pb + (size_t)s * kN * 80;
    union { uint4 v; _Float16 h[8]; } uu;
    uu.v = *(const uint4*)&ps[cg * 8];
    #pragma unroll
    for (int e = 0; e < 8; e++) accv[0][e] += (float)uu.h[e];
    if (cg == 0){
      uu.v = *(const uint4*)&ps[64];
      #pragma unroll
      for (int e = 0; e < 8; e++) accv[1][e] += (float)uu.h[e];
    }
  }
  // l = pacc col 66 = chunk 8 elem 2 (owned by cg==0); broadcast across 8-lane row group
  float l = accv[1][2];
  l = __shfl(l, lane & 56, 64);
  const float inv = 1.f / l;
  _Float16* orow = outb + (size_t)i * ostride + m * headoff;
  {
    union { uint4 v; _Float16 h[8]; } uu;
    #pragma unroll
    for (int e = 0; e < 8; e++){
      float v = accv[0][e] * inv;
      v = fmaxf(v, kSlope * v);
      uu.h[e] = (_Float16)v;
    }
    *(uint4*)&orow[cg * 8] = uu.v;
  }
  if (cg == 0){
    union { uint4 v; _Float16 h[8]; } uu;
    #pragma unroll
    for (int e = 0; e < 2; e++){
      float v = accv[1][e] * inv;
      v = fmaxf(v, kSlope * v);
      uu.h[e] = (_Float16)v;
    }
    uu.h[2] = (_Float16)(ones_col ? 1.f : 0.f);
    #pragma unroll
    for (int e = 3; e < 8; e++) uu.h[e] = (_Float16)0.f;
    *(uint4*)&orow[64] = uu.v;
  }
}

extern "C" void kernel_launch(void* const* d_in, const int* in_sizes, int n_in,
                              void* d_out, int out_size, void* d_ws, size_t ws_size,
                              hipStream_t stream){
  const float* inputs  = (const float*)d_in[0];
  const float* hx      = (const float*)d_in[1];
  const int*   adj     = (const int*)d_in[2];
  const float* m1_W    = (const float*)d_in[3];
  const float* m1_a1   = (const float*)d_in[4];
  const float* m1_a2   = (const float*)d_in[5];
  const float* m1_Wout = (const float*)d_in[6];
  const float* m1_ao1  = (const float*)d_in[7];
  const float* m1_ao2  = (const float*)d_in[8];
  const float* m2_W    = (const float*)d_in[9];
  const float* m2_a1   = (const float*)d_in[10];
  const float* m2_a2   = (const float*)d_in[11];
  const float* m2_Wout = (const float*)d_in[12];
  const float* m2_ao1  = (const float*)d_in[13];
  const float* m2_ao2  = (const float*)d_in[14];
  const float* g1_W    = (const float*)d_in[15];
  const float* g1_b    = (const float*)d_in[16];
  const float* g2_W    = (const float*)d_in[17];
  const float* g2_b    = (const float*)d_in[18];
  float* out = (float*)d_out;

  char* ws = (char*)d_ws;
  size_t off = 0;
  auto alloc = [&](size_t bytes) -> void* {
    void* p = ws + off;
    off = (off + bytes + 255) & ~(size_t)255;
    return p;
  };
  unsigned long long* packed = (unsigned long long*)alloc((size_t)kN * 64 * 8);
  _Float16* x1b  = (_Float16*)alloc((size_t)kN * 96 * 2);
  _Float16* x2b  = (_Float16*)alloc((size_t)kN * 96 * 2);
  _Float16* Ht   = (_Float16*)alloc((size_t)kH * 68 * kN * 2);
  _Float16* Hto  = (_Float16*)alloc((size_t)68 * kN * 2);
  _Float16* hcatb= (_Float16*)alloc((size_t)kN * 288 * 2);
  _Float16* gb   = (_Float16*)alloc((size_t)kN * 96 * 2);
  _Float16* g2bv = (_Float16*)alloc((size_t)kN * 96 * 2);
  float* f1   = (float*)alloc((size_t)kH * kN * 4);
  float* f2   = (float*)alloc((size_t)kH * kN * 4);
  float* fo1  = (float*)alloc((size_t)kN * 4);
  float* fo2  = (float*)alloc((size_t)kN * 4);
  unsigned int* fmaxbuf = (unsigned int*)alloc(64);
  float* u    = (float*)alloc((size_t)kN * kU * 4);
  _Float16* paccb = (_Float16*)alloc((size_t)16 * kN * 80 * 2);
  _Float16* B1t  = (_Float16*)alloc((size_t)kH * 80 * 96 * 2);
  _Float16* B1t2 = (_Float16*)alloc((size_t)kH * 80 * 96 * 2);
  _Float16* B2t  = (_Float16*)alloc((size_t)96 * 288 * 2);   // 96 rows: 16 pad rows for slab GEMM
  _Float16* B2t2 = (_Float16*)alloc((size_t)96 * 288 * 2);
  _Float16* Bgt  = (_Float16*)alloc((size_t)128 * 96 * 2);
  _Float16* Bft  = (_Float16*)alloc((size_t)64 * 96 * 2);
  (void)ws_size; (void)in_sizes; (void)n_in; (void)out_size;

  setup_k<<<16384 + 1024 + 12, 256, 0, stream>>>(adj, packed, inputs, hx, x1b, x2b,
      m1_W, m1_a1, m1_a2, m1_Wout, m1_ao1, m1_ao2,
      m2_W, m2_a1, m2_a2, m2_Wout, m2_ao1, m2_ao2,
      g1_W, g1_b, g2_W, g2_b,
      B1t, B1t2, B2t, B2t2, Bgt, Bft, fmaxbuf);

  // ---- subnet 1 ----
  gemm_k<3, 5, 0, false><<<dim3(64, kH), 256, 0, stream>>>(x1b, B1t, Ht, f1, f2, nullptr, fmaxbuf + 0);
  attn_mfma_k<4><<<dim3(64, kH, 4), 256, 0, stream>>>(Ht, f1, f2, fmaxbuf + 0, packed, paccb);
  combine_k<4><<<dim3(128, kH), 256, 0, stream>>>(paccb, hcatb, 288, 72, 0);
  gemm_k<9, 3, 0, true><<<dim3(64, 2), 256, 0, stream>>>(hcatb, B2t, Hto, fo1, fo2, nullptr, fmaxbuf + 4);
  attn_mfma_k<8><<<dim3(64, 1, 8), 256, 0, stream>>>(Hto, fo1, fo2, fmaxbuf + 4, packed, paccb);
  combine_k<8><<<dim3(128, 1), 256, 0, stream>>>(paccb, gb, 96, 0, 1);
  gemm_k<3, 4, 1, true><<<dim3(64, 2), 256, 0, stream>>>(gb, Bgt, u, x2b, nullptr, hx, nullptr);

  // ---- subnet 2 ----
  gemm_k<3, 5, 0, false><<<dim3(64, kH), 256, 0, stream>>>(x2b, B1t2, Ht, f1, f2, nullptr, fmaxbuf + 5);
  attn_mfma_k<4><<<dim3(64, kH, 4), 256, 0, stream>>>(Ht, f1, f2, fmaxbuf + 5, packed, paccb);
  combine_k<4><<<dim3(128, kH), 256, 0, stream>>>(paccb, hcatb, 288, 72, 0);
  gemm_k<9, 3, 0, true><<<dim3(64, 2), 256, 0, stream>>>(hcatb, B2t2, Hto, fo1, fo2, nullptr, fmaxbuf + 9);
  attn_mfma_k<8><<<dim3(64, 1, 8), 256, 0, stream>>>(Hto, fo1, fo2, fmaxbuf + 9, packed, paccb);
  combine_k<8><<<dim3(128, 1), 256, 0, stream>>>(paccb, g2bv, 96, 0, 1);
  gemm_k<3, 2, 2, true><<<dim3(64, 2), 256, 0, stream>>>(g2bv, Bft, out, u, nullptr, hx, nullptr);
}

// Round 7
// 297.995 us; speedup vs baseline: 1.3914x; 1.0109x over previous
//
#include <hip/hip_runtime.h>
#include <hip/hip_bf16.h>

constexpr int kN = 4096;
constexpr int kDim = 66;   // U + IN
constexpr int kH = 4;
constexpr int kU = 64;
constexpr float kAlpha = 0.2f;
constexpr float kSlope = 0.01f;
constexpr float kLog2e = 1.44269504f;

typedef _Float16 half8 __attribute__((ext_vector_type(8)));
typedef _Float16 half2t __attribute__((ext_vector_type(2)));
typedef __attribute__((ext_vector_type(4))) float floatx4;

__device__ inline unsigned int fkey(float f){ // monotone float->uint key for atomicMax
  unsigned int u = __float_as_uint(f);
  return (u & 0x80000000u) ? ~u : (u | 0x80000000u);
}
__device__ inline float funkey(unsigned int k){
  unsigned int u = (k & 0x80000000u) ? (k ^ 0x80000000u) : ~k;
  return __uint_as_float(u);
}

__device__ __forceinline__ void gld_lds16(const void* g, void* l){
  __builtin_amdgcn_global_load_lds((const __attribute__((address_space(1))) unsigned int*)g,
                                   (__attribute__((address_space(3))) unsigned int*)l, 16, 0, 0);
}

// ---------- merged setup: pack adjacency + build fp16 x1/x2 + all B matrices + fmax init ----------
__global__ void setup_k(const int* __restrict__ adj, unsigned long long* __restrict__ packed,
                        const float* __restrict__ in2, const float* __restrict__ hx,
                        _Float16* __restrict__ x1b, _Float16* __restrict__ x2b,
                        const float* __restrict__ m1W, const float* __restrict__ m1a1, const float* __restrict__ m1a2,
                        const float* __restrict__ m1Wo, const float* __restrict__ m1ao1, const float* __restrict__ m1ao2,
                        const float* __restrict__ m2W, const float* __restrict__ m2a1, const float* __restrict__ m2a2,
                        const float* __restrict__ m2Wo, const float* __restrict__ m2ao1, const float* __restrict__ m2ao2,
                        const float* __restrict__ g1W, const float* __restrict__ g1b,
                        const float* __restrict__ g2W, const float* __restrict__ g2b,
                        _Float16* __restrict__ B1t, _Float16* __restrict__ B1t2,
                        _Float16* __restrict__ B2t, _Float16* __restrict__ B2t2,
                        _Float16* __restrict__ Bgt, _Float16* __restrict__ Bft,
                        unsigned int* __restrict__ fmaxbuf){
  int bb = blockIdx.x, t = threadIdx.x;
  if (bb < 16384){
    int gid = bb * 256 + t;
    unsigned long long m = __ballot(adj[gid] != 0);
    if ((t & 63) == 0) packed[gid >> 6] = m;
    return;
  }
  if (bb < 16384 + 1024){
    int i = (bb - 16384) * 4 + (t >> 6);
    int c = t & 63;
    x1b[(size_t)i * 96 + 2 + c] = (_Float16)hx[(size_t)i * kU + c];
    if (c < 2){
      _Float16 xv = (_Float16)in2[i * 2 + c];
      x1b[(size_t)i * 96 + c] = xv;
      x2b[(size_t)i * 96 + c] = xv;
    }
    if (c < 30){ // zero pad cols 66..95 (harness poisons ws)
      x1b[(size_t)i * 96 + 66 + c] = (_Float16)0.f;
      x2b[(size_t)i * 96 + 66 + c] = (_Float16)0.f;
    }
    return;
  }
  int b = bb - (16384 + 1024);
  if (b < 8){
    int m = b & 3;
    const float* W  = (b < 4 ? m1W  : m2W)  + (size_t)m * kDim * kDim;
    const float* a1 = (b < 4 ? m1a1 : m2a1) + m * kDim;
    const float* a2 = (b < 4 ? m1a2 : m2a2) + m * kDim;
    _Float16* Bo = (b < 4 ? B1t : B1t2) + (size_t)m * 80 * 96;
    __shared__ float Ws[kDim * kDim];
    __shared__ float wa1s[kDim], wa2s[kDim];
    for (int z = t; z < kDim * kDim; z += 256) Ws[z] = W[z];
    __syncthreads();
    if (t < kDim){
      float s1 = 0.f, s2 = 0.f;
      for (int d = 0; d < kDim; d++){ float wv = Ws[t * kDim + d]; s1 += wv * a1[d]; s2 += wv * a2[d]; }
      wa1s[t] = s1; wa2s[t] = s2;
    }
    __syncthreads();
    for (int z = t; z < 80 * 96; z += 256){
      int nn = z / 96, k = z % 96;
      float val = 0.f;
      if (k < kDim){
        if (nn < kDim) val = Ws[k * kDim + nn];
        else if (nn == 66) val = wa1s[k];
        else if (nn == 67) val = wa2s[k];
      }
      Bo[z] = (_Float16)val;
    }
  } else if (b < 10){
    const float* Wo  = (b == 8 ? m1Wo  : m2Wo);
    const float* ao1 = (b == 8 ? m1ao1 : m2ao1);
    const float* ao2 = (b == 8 ? m1ao2 : m2ao2);
    _Float16* Bo = (b == 8 ? B2t : B2t2);
    __shared__ float wo1s[264], wo2s[264];
    for (int k = t; k < 264; k += 256){
      float s1 = 0.f, s2 = 0.f;
      for (int d = 0; d < kDim; d++){ float wv = Wo[(size_t)k * kDim + d]; s1 += wv * ao1[d]; s2 += wv * ao2[d]; }
      wo1s[k] = s1; wo2s[k] = s2;
    }
    __syncthreads();
    // K index is padded: k = h*72 + c, real Wout row = h*66 + c (c<66). Pad cols -> 0.
    for (int z = t; z < 80 * 288; z += 256){
      int nn = z / 288, k = z % 288;
      int h = k / 72, c = k - h * 72;
      float val = 0.f;
      if (c < 66){
        int kk = h * 66 + c;
        if (nn < kDim) val = Wo[(size_t)kk * kDim + nn];
        else if (nn == 66) val = wo1s[kk];
        else if (nn == 67) val = wo2s[kk];
      }
      Bo[z] = (_Float16)val;
    }
  } else if (b == 10){
    for (int z = t; z < 128 * 96; z += 256){
      int nn = z / 96, k = z % 96;
      float val = 0.f;
      if (k < kDim) val = g1W[k * 128 + nn];
      else if (k == 66) val = g1b[nn];
      Bgt[z] = (_Float16)val;
    }
  } else {
    if (t < 16) fmaxbuf[t] = 0u; // init max-key slots
    for (int z = t; z < 64 * 96; z += 256){
      int nn = z / 96, k = z % 96;
      float val = 0.f;
      if (k < kDim) val = g2W[k * 64 + nn];
      else if (k == 66) val = g2b[nn];
      Bft[z] = (_Float16)val;
    }
  }
}

// ---------- generic MFMA GEMM (fp16) with fused epilogues ----------
// EPI 0: -> Ht (fp16 transposed rows 0..67, row66=ones), f1,f2 (xlog2e, fp32), fmax atomic
// EPI 1: gate -> u = sigmoid; x2b cols 2..65 = sigmoid*hx (fp16)
// EPI 2: final -> out = u*hx + (1-u)*tanh(acc)
template<int KSTEPS, int NT, int EPI>
__global__ __launch_bounds__(256) void gemm_k(
    const _Float16* __restrict__ A, const _Float16* __restrict__ Bt,
    void* __restrict__ p0, void* __restrict__ p1, void* __restrict__ p2,
    const float* __restrict__ aux, unsigned int* __restrict__ fmaxp)
{
  constexpr int KP = KSTEPS * 32;
  const int m = blockIdx.y;
  const int i0 = blockIdx.x * 64;
  const int t = threadIdx.x;
  const int w = t >> 6, lane = t & 63, q = lane >> 4, n = lane & 15;
  const int arow = i0 + w * 16 + n;
  const _Float16* Ar = A + (size_t)arow * KP;
  const _Float16* Bm = Bt + (size_t)m * (NT * 16) * KP;
  floatx4 acc[NT];
  #pragma unroll
  for (int v = 0; v < NT; v++) acc[v] = (floatx4){0.f, 0.f, 0.f, 0.f};
  #pragma unroll
  for (int ks = 0; ks < KSTEPS; ks++){
    half8 af = *(const half8*)&Ar[ks * 32 + q * 8];
    #pragma unroll
    for (int nt = 0; nt < NT; nt++){
      half8 bf = *(const half8*)&Bm[(size_t)(nt * 16 + n) * KP + ks * 32 + q * 8];
      acc[nt] = __builtin_amdgcn_mfma_f32_16x16x32_f16(af, bf, acc[nt], 0, 0, 0);
    }
  }
  const int ib = i0 + w * 16 + q * 4; // D row base
  if constexpr (EPI == 0){
    _Float16* Ht = (_Float16*)p0 + (size_t)m * 68 * kN;
    float* f1 = (float*)p1 + (size_t)m * kN;
    float* f2 = (float*)p2 + (size_t)m * kN;
    float lm = -3e38f;
    #pragma unroll
    for (int nt = 0; nt < NT; nt++){
      int c = nt * 16 + n;
      if (c < kDim){
        union { _Float16 h[4]; uint2 v; } pk;
        pk.h[0] = (_Float16)acc[nt][0]; pk.h[1] = (_Float16)acc[nt][1];
        pk.h[2] = (_Float16)acc[nt][2]; pk.h[3] = (_Float16)acc[nt][3];
        *(uint2*)&Ht[(size_t)c * kN + ib] = pk.v;
      } else if (c == 66){
        float4 fv; fv.x = acc[nt][0] * kLog2e; fv.y = acc[nt][1] * kLog2e;
        fv.z = acc[nt][2] * kLog2e; fv.w = acc[nt][3] * kLog2e;
        *(float4*)&f1[ib] = fv;
        *(uint2*)&Ht[(size_t)66 * kN + ib] = make_uint2(0x3C003C00u, 0x3C003C00u); // fp16 ones
      } else if (c == 67){
        float4 fv; fv.x = acc[nt][0] * kLog2e; fv.y = acc[nt][1] * kLog2e;
        fv.z = acc[nt][2] * kLog2e; fv.w = acc[nt][3] * kLog2e;
        *(float4*)&f2[ib] = fv;
        lm = fmaxf(fmaxf(fv.x, fv.y), fmaxf(fv.z, fv.w));
        *(uint2*)&Ht[(size_t)67 * kN + ib] = make_uint2(0u, 0u);
      } // c >= 68: no store
    }
    lm = fmaxf(lm, __shfl_xor(lm, 16));
    lm = fmaxf(lm, __shfl_xor(lm, 32));
    if (lane == 3) atomicMax(&fmaxp[m], fkey(lm));
  } else if constexpr (EPI == 1){
    float* u = (float*)p0;
    _Float16* x2b = (_Float16*)p1;
    #pragma unroll
    for (int nt = 0; nt < NT; nt++){
      int c = nt * 16 + n;
      #pragma unroll
      for (int r = 0; r < 4; r++){
        float v = 1.f / (1.f + __expf(-acc[nt][r]));
        if (c < 64) x2b[(size_t)(ib + r) * 96 + 2 + c] = (_Float16)(v * aux[(size_t)(ib + r) * kU + c]);
        else        u[(size_t)(ib + r) * kU + (c - 64)] = v;
      }
    }
  } else {
    float* outp = (float*)p0;
    const float* u = (const float*)p1;
    #pragma unroll
    for (int nt = 0; nt < NT; nt++){
      int c = nt * 16 + n;
      #pragma unroll
      for (int r = 0; r < 4; r++){
        float cc = tanhf(acc[nt][r]);
        float uv = u[(size_t)(ib + r) * kU + c];
        outp[(size_t)(ib + r) * kU + c] = uv * aux[(size_t)(ib + r) * kU + c] + (1.f - uv) * cc;
      }
    }
  }
}

// ---------- MFMA attention (fp16, factorized softmax weights) ----------
// R1 pipeline, widened to 512 threads / 8 waves sharing one staged tile:
// per-CU staging traffic halves at identical waves/CU (attn<4>: 2 blk/CU x 8w = 16w/CU).
// glds double-buffered LDS staging, XOR-swizzled global source, swizzled ds_read_b128.
// p_ij = max(A1*B1_j, A2*B2_j); Ht row66=ones -> l_i.
template<int JSPLIT>
__global__ __launch_bounds__(512, 2) void attn_mfma_k(
    const _Float16* __restrict__ Ht, const float* __restrict__ f1,
    const float* __restrict__ f2, const unsigned int* __restrict__ fmaxu,
    const unsigned long long* __restrict__ packed,
    _Float16* __restrict__ paccb)
{
  constexpr int JR = kN / JSPLIT;      // j-range per block
  constexpr int NCH = JR / 128;        // 128-j chunks (even)
  const int m = blockIdx.y, js = blockIdx.z;
  const int i0 = blockIdx.x * 128;     // 128 i-rows per block (8 waves x 16)
  const int t = threadIdx.x;
  const int w = t >> 6, lane = t & 63, q = lane >> 4, n = lane & 15;
  const int i = i0 + w * 16 + n;
  const _Float16* Hg = Ht + (size_t)m * 68 * kN;
  const float* f2m = f2 + (size_t)m * kN;
  const float f1v = f1[(size_t)m * kN + i];   // pre-scaled by log2e
  const float fmx = funkey(fmaxu[m]);
  const float t0 = f1v + fmx;
  const float S = fmaxf(t0, kAlpha * t0);      // >= row max of scaled e
  const float A1f = __builtin_amdgcn_exp2f(t0 - S);
  const float A2f = __builtin_amdgcn_exp2f(kAlpha * t0 - S);
  const half2t a1p = { (_Float16)A1f, (_Float16)A1f };
  const half2t a2p = { (_Float16)A2f, (_Float16)A2f };

  __shared__ __align__(16) _Float16 buf[2][68 * 128];
  __shared__ __align__(16) _Float16 Zro[128];
  __shared__ __align__(16) _Float16 B1h[2][128], B2h[2][128];

  for (int z = t; z < 128; z += 512) Zro[z] = (_Float16)0.f;

  const int r4 = q;                 // lane>>4 : row-within-64-group
  const int cse = n ^ r4;           // col swizzle, even k (row&7 = r4)
  const int cso = cse ^ 4;          // odd k (row&7 = 4|r4)

  const int jbase = js * JR;
  const unsigned long long* prow = packed + (size_t)i * 64;
  const int jj = (w << 5) | (lane & 31);           // valid for w<4
  const bool blane = (w < 4) && ((lane & 32) == 0); // waves 0-3, lower halves: 128 lanes

  // glds: 17 calls cover rows 0..67 x 16 uint4, spread over 8 waves (<=3 each);
  // linear LDS dest, XOR-swizzled global src.
#define STAGE_G(PD, CH) do { \
    const _Float16* gB_ = Hg + jbase + (CH) * 128; \
    _Pragma("unroll") \
    for (int kk_ = 0; kk_ < 3; kk_++){ \
      const int k_ = w + kk_ * 8; \
      if (k_ < 17){ \
        const int row_ = k_ * 4 + r4; \
        const int csw_ = (k_ & 1) ? cso : cse; \
        gld_lds16(gB_ + (size_t)row_ * kN + csw_ * 8, &buf[(PD)][k_ * 512]); \
      } \
    } \
  } while (0)

  floatx4 acc[5];
  #pragma unroll
  for (int v = 0; v < 5; v++) acc[v] = (floatx4){0.f, 0.f, 0.f, 0.f};

  // prologue: stage chunk 0 into slot 0
  if (blane){
    const float v_ = f2m[jbase + jj] - fmx;
    B1h[0][jj] = (_Float16)__builtin_amdgcn_exp2f(v_);
    B2h[0][jj] = (_Float16)__builtin_amdgcn_exp2f(kAlpha * v_);
  }
  STAGE_G(0, 0);
  __syncthreads();

  int ch = 0;
#define BODY(P) do { \
    const int j0_ = jbase + ch * 128; \
    float f2v_ = 0.f; \
    const bool doB_ = (ch + 1 < NCH) && blane; \
    if (doB_) f2v_ = f2m[j0_ + 128 + jj]; \
    const unsigned long long w0_ = prow[j0_ >> 6]; \
    const unsigned long long w1_ = prow[(j0_ >> 6) + 1]; \
    __builtin_amdgcn_sched_barrier(0); \
    if (ch + 1 < NCH) STAGE_G((P) ^ 1, ch + 1); \
    __builtin_amdgcn_sched_barrier(0); \
    if (doB_){ \
      const float v_ = f2v_ - fmx; \
      B1h[(P) ^ 1][jj] = (_Float16)__builtin_amdgcn_exp2f(v_); \
      B2h[(P) ^ 1][jj] = (_Float16)__builtin_amdgcn_exp2f(kAlpha * v_); \
    } \
    const _Float16* bz_ = (n < 4) ? &buf[(P)][(64 + n) * 128] : Zro; \
    _Pragma("unroll") \
    for (int ks = 0; ks < 4; ks++){ \
      const unsigned long long wsel = (ks < 2) ? w0_ : w1_; \
      const unsigned int bits = (unsigned int)((wsel >> ((ks & 1) * 32 + q * 8)) & 0xffull); \
      union { uint4 v; unsigned int u[4]; } b1v, b2v; \
      b1v.v = *(const uint4*)&B1h[(P)][ks * 32 + q * 8]; \
      b2v.v = *(const uint4*)&B2h[(P)][ks * 32 + q * 8]; \
      union { half8 s; unsigned int u[4]; } af; \
      _Pragma("unroll") \
      for (int e = 0; e < 4; e++){ \
        half2t x1 = __builtin_bit_cast(half2t, b1v.u[e]); \
        half2t x2 = __builtin_bit_cast(half2t, b2v.u[e]); \
        half2t m1 = x1 * a1p; \
        half2t m2 = x2 * a2p; \
        half2t pm = __builtin_elementwise_max(m1, m2); \
        unsigned int mm = (((bits >> (2 * e)) & 1u) ? 0x0000FFFFu : 0u) \
                        | (((bits >> (2 * e + 1)) & 1u) ? 0xFFFF0000u : 0u); \
        af.u[e] = __builtin_bit_cast(unsigned int, pm) & mm; \
      } \
      const int cs_ = ((ks * 4 + q) ^ (n & 7)) * 8; \
      _Pragma("unroll") \
      for (int nt = 0; nt < 4; nt++){ \
        const half8 bf = *(const half8*)&buf[(P)][(nt * 16 + n) * 128 + cs_]; \
        acc[nt] = __builtin_amdgcn_mfma_f32_16x16x32_f16(af.s, bf, acc[nt], 0, 0, 0); \
      } \
      { const half8 bf4 = *(const half8*)&bz_[cs_]; \
        acc[4] = __builtin_amdgcn_mfma_f32_16x16x32_f16(af.s, bf4, acc[4], 0, 0, 0); } \
    } \
    ch++; \
    if (ch < NCH) __syncthreads(); \
  } while (0)

  #pragma unroll 1
  for (int it = 0; it < NCH / 2; it++){
    BODY(0);
    BODY(1);
  }
#undef BODY
#undef STAGE_G

  _Float16* pw = paccb + ((size_t)(m * JSPLIT + js) * kN + (i0 + w * 16)) * 80;
  #pragma unroll
  for (int nt = 0; nt < 5; nt++){
    if (nt < 4 || n < 4){ // cols >= 68 are unused
      #pragma unroll
      for (int r = 0; r < 4; r++)
        pw[(q * 4 + r) * 80 + nt * 16 + n] = (_Float16)acc[nt][r];
    }
  }
}

// ---------- combine j-split fp16 partials -> lrelu -> fp16 rows (vectorized) ----------
// 64 rows x 4 lanes per block; uint4 loads from 80-stride pacc rows; uint4 stores.
// Writes 9 chunks (72 cols) per head slice; chunk 8: e2 = ones/0, e3..7 = 0.
template<int JSPLIT>
__global__ void combine_k(const _Float16* __restrict__ paccb, _Float16* __restrict__ outb,
                          int ostride, int headoff, int ones_col){
  const int m = blockIdx.y;
  const int t = threadIdx.x;
  const int ri = t >> 2, cg = t & 3;
  const int lane = t & 63;
  const int i = blockIdx.x * 64 + ri;
  const _Float16* pb = paccb + ((size_t)m * JSPLIT * kN + i) * 80;
  float accv[3][8];
  #pragma unroll
  for (int k = 0; k < 3; k++)
    #pragma unroll
    for (int e = 0; e < 8; e++) accv[k][e] = 0.f;
  #pragma unroll
  for (int s = 0; s < JSPLIT; s++){
    const _Float16* ps = pb + (size_t)s * kN * 80;
    #pragma unroll
    for (int k = 0; k < 3; k++){
      const int c = cg + 4 * k;
      if (c < 9){
        union { uint4 v; _Float16 h[8]; } uu;
        uu.v = *(const uint4*)&ps[c * 8];
        #pragma unroll
        for (int e = 0; e < 8; e++) accv[k][e] += (float)uu.h[e];
      }
    }
  }
  // l = pacc col 66 = chunk 8 elem 2 (owned by cg==0, k==2); broadcast in wave
  float l = accv[2][2];
  l = __shfl(l, lane & ~3, 64);
  const float inv = 1.f / l;
  _Float16* orow = outb + (size_t)i * ostride + m * headoff;
  #pragma unroll
  for (int k = 0; k < 3; k++){
    const int c = cg + 4 * k;
    if (c < 9){
      union { uint4 v; _Float16 h[8]; } uu;
      #pragma unroll
      for (int e = 0; e < 8; e++){
        float v = accv[k][e] * inv;
        v = fmaxf(v, kSlope * v);
        uu.h[e] = (_Float16)v;
      }
      if (c == 8){
        uu.h[2] = (_Float16)(ones_col ? 1.f : 0.f);
        #pragma unroll
        for (int e = 3; e < 8; e++) uu.h[e] = (_Float16)0.f;
      }
      *(uint4*)&orow[c * 8] = uu.v;
    }
  }
}

extern "C" void kernel_launch(void* const* d_in, const int* in_sizes, int n_in,
                              void* d_out, int out_size, void* d_ws, size_t ws_size,
                              hipStream_t stream){
  const float* inputs  = (const float*)d_in[0];
  const float* hx      = (const float*)d_in[1];
  const int*   adj     = (const int*)d_in[2];
  const float* m1_W    = (const float*)d_in[3];
  const float* m1_a1   = (const float*)d_in[4];
  const float* m1_a2   = (const float*)d_in[5];
  const float* m1_Wout = (const float*)d_in[6];
  const float* m1_ao1  = (const float*)d_in[7];
  const float* m1_ao2  = (const float*)d_in[8];
  const float* m2_W    = (const float*)d_in[9];
  const float* m2_a1   = (const float*)d_in[10];
  const float* m2_a2   = (const float*)d_in[11];
  const float* m2_Wout = (const float*)d_in[12];
  const float* m2_ao1  = (const float*)d_in[13];
  const float* m2_ao2  = (const float*)d_in[14];
  const float* g1_W    = (const float*)d_in[15];
  const float* g1_b    = (const float*)d_in[16];
  const float* g2_W    = (const float*)d_in[17];
  const float* g2_b    = (const float*)d_in[18];
  float* out = (float*)d_out;

  char* ws = (char*)d_ws;
  size_t off = 0;
  auto alloc = [&](size_t bytes) -> void* {
    void* p = ws + off;
    off = (off + bytes + 255) & ~(size_t)255;
    return p;
  };
  unsigned long long* packed = (unsigned long long*)alloc((size_t)kN * 64 * 8);
  _Float16* x1b  = (_Float16*)alloc((size_t)kN * 96 * 2);
  _Float16* x2b  = (_Float16*)alloc((size_t)kN * 96 * 2);
  _Float16* Ht   = (_Float16*)alloc((size_t)kH * 68 * kN * 2);
  _Float16* Hto  = (_Float16*)alloc((size_t)68 * kN * 2);
  _Float16* hcatb= (_Float16*)alloc((size_t)kN * 288 * 2);
  _Float16* gb   = (_Float16*)alloc((size_t)kN * 96 * 2);
  _Float16* g2bv = (_Float16*)alloc((size_t)kN * 96 * 2);
  float* f1   = (float*)alloc((size_t)kH * kN * 4);
  float* f2   = (float*)alloc((size_t)kH * kN * 4);
  float* fo1  = (float*)alloc((size_t)kN * 4);
  float* fo2  = (float*)alloc((size_t)kN * 4);
  unsigned int* fmaxbuf = (unsigned int*)alloc(64);
  float* u    = (float*)alloc((size_t)kN * kU * 4);
  _Float16* paccb = (_Float16*)alloc((size_t)16 * kN * 80 * 2);
  _Float16* B1t  = (_Float16*)alloc((size_t)kH * 80 * 96 * 2);
  _Float16* B1t2 = (_Float16*)alloc((size_t)kH * 80 * 96 * 2);
  _Float16* B2t  = (_Float16*)alloc((size_t)80 * 288 * 2);
  _Float16* B2t2 = (_Float16*)alloc((size_t)80 * 288 * 2);
  _Float16* Bgt  = (_Float16*)alloc((size_t)128 * 96 * 2);
  _Float16* Bft  = (_Float16*)alloc((size_t)64 * 96 * 2);
  (void)ws_size; (void)in_sizes; (void)n_in; (void)out_size;

  setup_k<<<16384 + 1024 + 12, 256, 0, stream>>>(adj, packed, inputs, hx, x1b, x2b,
      m1_W, m1_a1, m1_a2, m1_Wout, m1_ao1, m1_ao2,
      m2_W, m2_a1, m2_a2, m2_Wout, m2_ao1, m2_ao2,
      g1_W, g1_b, g2_W, g2_b,
      B1t, B1t2, B2t, B2t2, Bgt, Bft, fmaxbuf);

  // ---- subnet 1 ----
  gemm_k<3, 5, 0><<<dim3(64, kH), 256, 0, stream>>>(x1b, B1t, Ht, f1, f2, nullptr, fmaxbuf + 0);
  attn_mfma_k<4><<<dim3(32, kH, 4), 512, 0, stream>>>(Ht, f1, f2, fmaxbuf + 0, packed, paccb);
  combine_k<4><<<dim3(64, kH), 256, 0, stream>>>(paccb, hcatb, 288, 72, 0);
  gemm_k<9, 5, 0><<<dim3(64, 1), 256, 0, stream>>>(hcatb, B2t, Hto, fo1, fo2, nullptr, fmaxbuf + 4);
  attn_mfma_k<8><<<dim3(32, 1, 8), 512, 0, stream>>>(Hto, fo1, fo2, fmaxbuf + 4, packed, paccb);
  combine_k<8><<<dim3(64, 1), 256, 0, stream>>>(paccb, gb, 96, 0, 1);
  gemm_k<3, 8, 1><<<dim3(64, 1), 256, 0, stream>>>(gb, Bgt, u, x2b, nullptr, hx, nullptr);

  // ---- subnet 2 ----
  gemm_k<3, 5, 0><<<dim3(64, kH), 256, 0, stream>>>(x2b, B1t2, Ht, f1, f2, nullptr, fmaxbuf + 5);
  attn_mfma_k<4><<<dim3(32, kH, 4), 512, 0, stream>>>(Ht, f1, f2, fmaxbuf + 5, packed, paccb);
  combine_k<4><<<dim3(64, kH), 256, 0, stream>>>(paccb, hcatb, 288, 72, 0);
  gemm_k<9, 5, 0><<<dim3(64, 1), 256, 0, stream>>>(hcatb, B2t2, Hto, fo1, fo2, nullptr, fmaxbuf + 9);
  attn_mfma_k<8><<<dim3(32, 1, 8), 512, 0, stream>>>(Hto, fo1, fo2, fmaxbuf + 9, packed, paccb);
  combine_k<8><<<dim3(64, 1), 256, 0, stream>>>(paccb, g2bv, 96, 0, 1);
  gemm_k<3, 4, 2><<<dim3(64, 1), 256, 0, stream>>>(g2bv, Bft, out, u, nullptr, hx, nullptr);
}

// Round 8
// 293.743 us; speedup vs baseline: 1.4116x; 1.0145x over previous
//
#include <hip/hip_runtime.h>
#include <hip/hip_bf16.h>

constexpr int kN = 4096;
constexpr int kDim = 66;   // U + IN
constexpr int kH = 4;
constexpr int kU = 64;
constexpr float kAlpha = 0.2f;
constexpr float kSlope = 0.01f;
constexpr float kLog2e = 1.44269504f;

typedef _Float16 half8 __attribute__((ext_vector_type(8)));
typedef _Float16 half2t __attribute__((ext_vector_type(2)));
typedef __attribute__((ext_vector_type(4))) float floatx4;

__device__ inline unsigned int fkey(float f){ // monotone float->uint key for atomicMax
  unsigned int u = __float_as_uint(f);
  return (u & 0x80000000u) ? ~u : (u | 0x80000000u);
}
__device__ inline float funkey(unsigned int k){
  unsigned int u = (k & 0x80000000u) ? (k ^ 0x80000000u) : ~k;
  return __uint_as_float(u);
}

__device__ __forceinline__ void gld_lds16(const void* g, void* l){
  __builtin_amdgcn_global_load_lds((const __attribute__((address_space(1))) unsigned int*)g,
                                   (__attribute__((address_space(3))) unsigned int*)l, 16, 0, 0);
}

// ---------- merged setup: pack adjacency + build fp16 x1/x2 + all B matrices + fmax init ----------
__global__ void setup_k(const int* __restrict__ adj, unsigned long long* __restrict__ packed,
                        const float* __restrict__ in2, const float* __restrict__ hx,
                        _Float16* __restrict__ x1b, _Float16* __restrict__ x2b,
                        const float* __restrict__ m1W, const float* __restrict__ m1a1, const float* __restrict__ m1a2,
                        const float* __restrict__ m1Wo, const float* __restrict__ m1ao1, const float* __restrict__ m1ao2,
                        const float* __restrict__ m2W, const float* __restrict__ m2a1, const float* __restrict__ m2a2,
                        const float* __restrict__ m2Wo, const float* __restrict__ m2ao1, const float* __restrict__ m2ao2,
                        const float* __restrict__ g1W, const float* __restrict__ g1b,
                        const float* __restrict__ g2W, const float* __restrict__ g2b,
                        _Float16* __restrict__ B1t, _Float16* __restrict__ B1t2,
                        _Float16* __restrict__ B2t, _Float16* __restrict__ B2t2,
                        _Float16* __restrict__ Bgt, _Float16* __restrict__ Bft,
                        unsigned int* __restrict__ fmaxbuf){
  int bb = blockIdx.x, t = threadIdx.x;
  if (bb < 16384){
    int gid = bb * 256 + t;
    unsigned long long m = __ballot(adj[gid] != 0);
    if ((t & 63) == 0) packed[gid >> 6] = m;
    return;
  }
  if (bb < 16384 + 1024){
    int i = (bb - 16384) * 4 + (t >> 6);
    int c = t & 63;
    x1b[(size_t)i * 96 + 2 + c] = (_Float16)hx[(size_t)i * kU + c];
    if (c < 2){
      _Float16 xv = (_Float16)in2[i * 2 + c];
      x1b[(size_t)i * 96 + c] = xv;
      x2b[(size_t)i * 96 + c] = xv;
    }
    if (c < 30){ // zero pad cols 66..95 (harness poisons ws)
      x1b[(size_t)i * 96 + 66 + c] = (_Float16)0.f;
      x2b[(size_t)i * 96 + 66 + c] = (_Float16)0.f;
    }
    return;
  }
  int b = bb - (16384 + 1024);
  if (b < 8){
    int m = b & 3;
    const float* W  = (b < 4 ? m1W  : m2W)  + (size_t)m * kDim * kDim;
    const float* a1 = (b < 4 ? m1a1 : m2a1) + m * kDim;
    const float* a2 = (b < 4 ? m1a2 : m2a2) + m * kDim;
    _Float16* Bo = (b < 4 ? B1t : B1t2) + (size_t)m * 80 * 96;
    __shared__ float Ws[kDim * kDim];
    __shared__ float wa1s[kDim], wa2s[kDim];
    for (int z = t; z < kDim * kDim; z += 256) Ws[z] = W[z];
    __syncthreads();
    if (t < kDim){
      float s1 = 0.f, s2 = 0.f;
      for (int d = 0; d < kDim; d++){ float wv = Ws[t * kDim + d]; s1 += wv * a1[d]; s2 += wv * a2[d]; }
      wa1s[t] = s1; wa2s[t] = s2;
    }
    __syncthreads();
    for (int z = t; z < 80 * 96; z += 256){
      int nn = z / 96, k = z % 96;
      float val = 0.f;
      if (k < kDim){
        if (nn < kDim) val = Ws[k * kDim + nn];
        else if (nn == 66) val = wa1s[k];
        else if (nn == 67) val = wa2s[k];
      }
      Bo[z] = (_Float16)val;
    }
  } else if (b < 10){
    const float* Wo  = (b == 8 ? m1Wo  : m2Wo);
    const float* ao1 = (b == 8 ? m1ao1 : m2ao1);
    const float* ao2 = (b == 8 ? m1ao2 : m2ao2);
    _Float16* Bo = (b == 8 ? B2t : B2t2);
    __shared__ float wo1s[264], wo2s[264];
    for (int k = t; k < 264; k += 256){
      float s1 = 0.f, s2 = 0.f;
      for (int d = 0; d < kDim; d++){ float wv = Wo[(size_t)k * kDim + d]; s1 += wv * ao1[d]; s2 += wv * ao2[d]; }
      wo1s[k] = s1; wo2s[k] = s2;
    }
    __syncthreads();
    // K index is padded: k = h*72 + c, real Wout row = h*66 + c (c<66). Pad cols -> 0.
    for (int z = t; z < 80 * 288; z += 256){
      int nn = z / 288, k = z % 288;
      int h = k / 72, c = k - h * 72;
      float val = 0.f;
      if (c < 66){
        int kk = h * 66 + c;
        if (nn < kDim) val = Wo[(size_t)kk * kDim + nn];
        else if (nn == 66) val = wo1s[kk];
        else if (nn == 67) val = wo2s[kk];
      }
      Bo[z] = (_Float16)val;
    }
  } else if (b == 10){
    for (int z = t; z < 128 * 96; z += 256){
      int nn = z / 96, k = z % 96;
      float val = 0.f;
      if (k < kDim) val = g1W[k * 128 + nn];
      else if (k == 66) val = g1b[nn];
      Bgt[z] = (_Float16)val;
    }
  } else {
    if (t < 16) fmaxbuf[t] = 0u; // init max-key slots
    for (int z = t; z < 64 * 96; z += 256){
      int nn = z / 96, k = z % 96;
      float val = 0.f;
      if (k < kDim) val = g2W[k * 64 + nn];
      else if (k == 66) val = g2b[nn];
      Bft[z] = (_Float16)val;
    }
  }
}

// ---------- generic MFMA GEMM (fp16) with fused epilogues ----------
// EPI 0: -> Ht (fp16 transposed rows 0..67, row66=ones), f1,f2 (xlog2e, fp32), fmax atomic
// EPI 1: gate -> u = sigmoid; x2b cols 2..65 = sigmoid*hx (fp16)
// EPI 2: final -> out = u*hx + (1-u)*tanh(acc)
template<int KSTEPS, int NT, int EPI>
__global__ __launch_bounds__(256) void gemm_k(
    const _Float16* __restrict__ A, const _Float16* __restrict__ Bt,
    void* __restrict__ p0, void* __restrict__ p1, void* __restrict__ p2,
    const float* __restrict__ aux, unsigned int* __restrict__ fmaxp)
{
  constexpr int KP = KSTEPS * 32;
  const int m = blockIdx.y;
  const int i0 = blockIdx.x * 64;
  const int t = threadIdx.x;
  const int w = t >> 6, lane = t & 63, q = lane >> 4, n = lane & 15;
  const int arow = i0 + w * 16 + n;
  const _Float16* Ar = A + (size_t)arow * KP;
  const _Float16* Bm = Bt + (size_t)m * (NT * 16) * KP;
  floatx4 acc[NT];
  #pragma unroll
  for (int v = 0; v < NT; v++) acc[v] = (floatx4){0.f, 0.f, 0.f, 0.f};
  #pragma unroll
  for (int ks = 0; ks < KSTEPS; ks++){
    half8 af = *(const half8*)&Ar[ks * 32 + q * 8];
    #pragma unroll
    for (int nt = 0; nt < NT; nt++){
      half8 bf = *(const half8*)&Bm[(size_t)(nt * 16 + n) * KP + ks * 32 + q * 8];
      acc[nt] = __builtin_amdgcn_mfma_f32_16x16x32_f16(af, bf, acc[nt], 0, 0, 0);
    }
  }
  const int ib = i0 + w * 16 + q * 4; // D row base
  if constexpr (EPI == 0){
    _Float16* Ht = (_Float16*)p0 + (size_t)m * 68 * kN;
    float* f1 = (float*)p1 + (size_t)m * kN;
    float* f2 = (float*)p2 + (size_t)m * kN;
    float lm = -3e38f;
    #pragma unroll
    for (int nt = 0; nt < NT; nt++){
      int c = nt * 16 + n;
      if (c < kDim){
        union { _Float16 h[4]; uint2 v; } pk;
        pk.h[0] = (_Float16)acc[nt][0]; pk.h[1] = (_Float16)acc[nt][1];
        pk.h[2] = (_Float16)acc[nt][2]; pk.h[3] = (_Float16)acc[nt][3];
        *(uint2*)&Ht[(size_t)c * kN + ib] = pk.v;
      } else if (c == 66){
        float4 fv; fv.x = acc[nt][0] * kLog2e; fv.y = acc[nt][1] * kLog2e;
        fv.z = acc[nt][2] * kLog2e; fv.w = acc[nt][3] * kLog2e;
        *(float4*)&f1[ib] = fv;
        *(uint2*)&Ht[(size_t)66 * kN + ib] = make_uint2(0x3C003C00u, 0x3C003C00u); // fp16 ones
      } else if (c == 67){
        float4 fv; fv.x = acc[nt][0] * kLog2e; fv.y = acc[nt][1] * kLog2e;
        fv.z = acc[nt][2] * kLog2e; fv.w = acc[nt][3] * kLog2e;
        *(float4*)&f2[ib] = fv;
        lm = fmaxf(fmaxf(fv.x, fv.y), fmaxf(fv.z, fv.w));
        *(uint2*)&Ht[(size_t)67 * kN + ib] = make_uint2(0u, 0u);
      } // c >= 68: no store
    }
    lm = fmaxf(lm, __shfl_xor(lm, 16));
    lm = fmaxf(lm, __shfl_xor(lm, 32));
    if (lane == 3) atomicMax(&fmaxp[m], fkey(lm));
  } else if constexpr (EPI == 1){
    float* u = (float*)p0;
    _Float16* x2b = (_Float16*)p1;
    #pragma unroll
    for (int nt = 0; nt < NT; nt++){
      int c = nt * 16 + n;
      #pragma unroll
      for (int r = 0; r < 4; r++){
        float v = 1.f / (1.f + __expf(-acc[nt][r]));
        if (c < 64) x2b[(size_t)(ib + r) * 96 + 2 + c] = (_Float16)(v * aux[(size_t)(ib + r) * kU + c]);
        else        u[(size_t)(ib + r) * kU + (c - 64)] = v;
      }
    }
  } else {
    float* outp = (float*)p0;
    const float* u = (const float*)p1;
    #pragma unroll
    for (int nt = 0; nt < NT; nt++){
      int c = nt * 16 + n;
      #pragma unroll
      for (int r = 0; r < 4; r++){
        float cc = tanhf(acc[nt][r]);
        float uv = u[(size_t)(ib + r) * kU + c];
        outp[(size_t)(ib + r) * kU + c] = uv * aux[(size_t)(ib + r) * kU + c] + (1.f - uv) * cc;
      }
    }
  }
}

// ---------- MFMA attention (fp16, factorized softmax weights) ----------
// p_ij = exp2(lrelu(f1+f2)-S) = max(A1*B1_j, A2*B2_j); col 66 of Ht = ones -> l_i
// Double-buffered LDS via global_load_lds with XOR-swizzled global source
// (linear LDS dest, per m173), swizzled ds_read_b128 on the consume side.
template<int JSPLIT>
__global__ __launch_bounds__(256, 4) void attn_mfma_k(
    const _Float16* __restrict__ Ht, const float* __restrict__ f1,
    const float* __restrict__ f2, const unsigned int* __restrict__ fmaxu,
    const unsigned long long* __restrict__ packed,
    _Float16* __restrict__ paccb)
{
  constexpr int JR = kN / JSPLIT;      // j-range per block
  constexpr int NCH = JR / 128;        // 128-j chunks (even)
  const int m = blockIdx.y, js = blockIdx.z;
  const int i0 = blockIdx.x * 64;
  const int t = threadIdx.x;
  const int w = t >> 6, lane = t & 63, q = lane >> 4, n = lane & 15;
  const int i = i0 + w * 16 + n;
  const _Float16* Hg = Ht + (size_t)m * 68 * kN;
  const float* f2m = f2 + (size_t)m * kN;
  const float f1v = f1[(size_t)m * kN + i];   // pre-scaled by log2e
  const float fmx = funkey(fmaxu[m]);
  const float t0 = f1v + fmx;
  const float S = fmaxf(t0, kAlpha * t0);      // >= row max of scaled e
  const float A1f = __builtin_amdgcn_exp2f(t0 - S);
  const float A2f = __builtin_amdgcn_exp2f(kAlpha * t0 - S);
  const half2t a1p = { (_Float16)A1f, (_Float16)A1f };
  const half2t a2p = { (_Float16)A2f, (_Float16)A2f };

  __shared__ __align__(16) _Float16 buf[2][68 * 128];
  __shared__ __align__(16) _Float16 Zro[128];
  __shared__ __align__(16) _Float16 B1h[2][128], B2h[2][128];

  for (int z = t; z < 128; z += 256) Zro[z] = (_Float16)0.f;

  const int r4 = q;                 // lane>>4 : row-within-64-group
  const int cse = n ^ r4;           // col swizzle, even k (row&7 = r4)
  const int cso = cse ^ 4;          // odd k (row&7 = 4|r4)

  const int jbase = js * JR;
  const unsigned long long* prow = packed + (size_t)i * 64;
  const int jj = (w << 5) | (lane & 31);
  const bool blane = (lane & 32) == 0;

  // glds: 17 calls cover rows 0..67 x 16 uint4; linear LDS dest, XOR-swizzled global src.
#define STAGE_G(PD, CH) do { \
    const _Float16* gB_ = Hg + jbase + (CH) * 128; \
    _Pragma("unroll") \
    for (int kk_ = 0; kk_ < 5; kk_++){ \
      const int k_ = w + kk_ * 4; \
      if (k_ < 17){ \
        const int row_ = k_ * 4 + r4; \
        const int csw_ = (k_ & 1) ? cso : cse; \
        gld_lds16(gB_ + (size_t)row_ * kN + csw_ * 8, &buf[(PD)][k_ * 512]); \
      } \
    } \
  } while (0)

  floatx4 acc[5];
  #pragma unroll
  for (int v = 0; v < 5; v++) acc[v] = (floatx4){0.f, 0.f, 0.f, 0.f};

  // prologue: stage chunk 0 into slot 0
  if (blane){
    const float v_ = f2m[jbase + jj] - fmx;
    B1h[0][jj] = (_Float16)__builtin_amdgcn_exp2f(v_);
    B2h[0][jj] = (_Float16)__builtin_amdgcn_exp2f(kAlpha * v_);
  }
  STAGE_G(0, 0);
  __syncthreads();

  int ch = 0;
#define BODY(P) do { \
    const int j0_ = jbase + ch * 128; \
    float f2v_ = 0.f; \
    const bool doB_ = (ch + 1 < NCH) && blane; \
    if (doB_) f2v_ = f2m[j0_ + 128 + jj]; \
    const unsigned long long w0_ = prow[j0_ >> 6]; \
    const unsigned long long w1_ = prow[(j0_ >> 6) + 1]; \
    __builtin_amdgcn_sched_barrier(0); \
    if (ch + 1 < NCH) STAGE_G((P) ^ 1, ch + 1); \
    __builtin_amdgcn_sched_barrier(0); \
    if (doB_){ \
      const float v_ = f2v_ - fmx; \
      B1h[(P) ^ 1][jj] = (_Float16)__builtin_amdgcn_exp2f(v_); \
      B2h[(P) ^ 1][jj] = (_Float16)__builtin_amdgcn_exp2f(kAlpha * v_); \
    } \
    const _Float16* bz_ = (n < 4) ? &buf[(P)][(64 + n) * 128] : Zro; \
    _Pragma("unroll") \
    for (int ks = 0; ks < 4; ks++){ \
      const unsigned long long wsel = (ks < 2) ? w0_ : w1_; \
      const unsigned int bits = (unsigned int)((wsel >> ((ks & 1) * 32 + q * 8)) & 0xffull); \
      union { uint4 v; unsigned int u[4]; } b1v, b2v; \
      b1v.v = *(const uint4*)&B1h[(P)][ks * 32 + q * 8]; \
      b2v.v = *(const uint4*)&B2h[(P)][ks * 32 + q * 8]; \
      union { half8 s; unsigned int u[4]; } af; \
      _Pragma("unroll") \
      for (int e = 0; e < 4; e++){ \
        half2t x1 = __builtin_bit_cast(half2t, b1v.u[e]); \
        half2t x2 = __builtin_bit_cast(half2t, b2v.u[e]); \
        half2t m1 = x1 * a1p; \
        half2t m2 = x2 * a2p; \
        half2t pm = __builtin_elementwise_max(m1, m2); \
        unsigned int mm = (((bits >> (2 * e)) & 1u) ? 0x0000FFFFu : 0u) \
                        | (((bits >> (2 * e + 1)) & 1u) ? 0xFFFF0000u : 0u); \
        af.u[e] = __builtin_bit_cast(unsigned int, pm) & mm; \
      } \
      const int cs_ = ((ks * 4 + q) ^ (n & 7)) * 8; \
      _Pragma("unroll") \
      for (int nt = 0; nt < 4; nt++){ \
        const half8 bf = *(const half8*)&buf[(P)][(nt * 16 + n) * 128 + cs_]; \
        acc[nt] = __builtin_amdgcn_mfma_f32_16x16x32_f16(af.s, bf, acc[nt], 0, 0, 0); \
      } \
      { const half8 bf4 = *(const half8*)&bz_[cs_]; \
        acc[4] = __builtin_amdgcn_mfma_f32_16x16x32_f16(af.s, bf4, acc[4], 0, 0, 0); } \
    } \
    ch++; \
    if (ch < NCH) __syncthreads(); \
  } while (0)

  #pragma unroll 1
  for (int it = 0; it < NCH / 2; it++){
    BODY(0);
    BODY(1);
  }
#undef BODY
#undef STAGE_G

  _Float16* pw = paccb + ((size_t)(m * JSPLIT + js) * kN + (i0 + w * 16)) * 80;
  #pragma unroll
  for (int nt = 0; nt < 5; nt++){
    if (nt < 4 || n < 4){ // cols >= 68 are unused
      #pragma unroll
      for (int r = 0; r < 4; r++)
        pw[(q * 4 + r) * 80 + nt * 16 + n] = (_Float16)acc[nt][r];
    }
  }
}

// ---------- combine j-split fp16 partials -> lrelu -> fp16 rows (vectorized) ----------
// 64 rows x 4 lanes per block; uint4 loads from 80-stride pacc rows; uint4 stores.
// Writes 9 chunks (72 cols) per head slice; chunk 8: e2 = ones/0, e3..7 = 0.
template<int JSPLIT>
__global__ void combine_k(const _Float16* __restrict__ paccb, _Float16* __restrict__ outb,
                          int ostride, int headoff, int ones_col){
  const int m = blockIdx.y;
  const int t = threadIdx.x;
  const int ri = t >> 2, cg = t & 3;
  const int lane = t & 63;
  const int i = blockIdx.x * 64 + ri;
  const _Float16* pb = paccb + ((size_t)m * JSPLIT * kN + i) * 80;
  float accv[3][8];
  #pragma unroll
  for (int k = 0; k < 3; k++)
    #pragma unroll
    for (int e = 0; e < 8; e++) accv[k][e] = 0.f;
  #pragma unroll
  for (int s = 0; s < JSPLIT; s++){
    const _Float16* ps = pb + (size_t)s * kN * 80;
    #pragma unroll
    for (int k = 0; k < 3; k++){
      const int c = cg + 4 * k;
      if (c < 9){
        union { uint4 v; _Float16 h[8]; } uu;
        uu.v = *(const uint4*)&ps[c * 8];
        #pragma unroll
        for (int e = 0; e < 8; e++) accv[k][e] += (float)uu.h[e];
      }
    }
  }
  // l = pacc col 66 = chunk 8 elem 2 (owned by cg==0, k==2); broadcast in wave
  float l = accv[2][2];
  l = __shfl(l, lane & ~3, 64);
  const float inv = 1.f / l;
  _Float16* orow = outb + (size_t)i * ostride + m * headoff;
  #pragma unroll
  for (int k = 0; k < 3; k++){
    const int c = cg + 4 * k;
    if (c < 9){
      union { uint4 v; _Float16 h[8]; } uu;
      #pragma unroll
      for (int e = 0; e < 8; e++){
        float v = accv[k][e] * inv;
        v = fmaxf(v, kSlope * v);
        uu.h[e] = (_Float16)v;
      }
      if (c == 8){
        uu.h[2] = (_Float16)(ones_col ? 1.f : 0.f);
        #pragma unroll
        for (int e = 3; e < 8; e++) uu.h[e] = (_Float16)0.f;
      }
      *(uint4*)&orow[c * 8] = uu.v;
    }
  }
}

extern "C" void kernel_launch(void* const* d_in, const int* in_sizes, int n_in,
                              void* d_out, int out_size, void* d_ws, size_t ws_size,
                              hipStream_t stream){
  const float* inputs  = (const float*)d_in[0];
  const float* hx      = (const float*)d_in[1];
  const int*   adj     = (const int*)d_in[2];
  const float* m1_W    = (const float*)d_in[3];
  const float* m1_a1   = (const float*)d_in[4];
  const float* m1_a2   = (const float*)d_in[5];
  const float* m1_Wout = (const float*)d_in[6];
  const float* m1_ao1  = (const float*)d_in[7];
  const float* m1_ao2  = (const float*)d_in[8];
  const float* m2_W    = (const float*)d_in[9];
  const float* m2_a1   = (const float*)d_in[10];
  const float* m2_a2   = (const float*)d_in[11];
  const float* m2_Wout = (const float*)d_in[12];
  const float* m2_ao1  = (const float*)d_in[13];
  const float* m2_ao2  = (const float*)d_in[14];
  const float* g1_W    = (const float*)d_in[15];
  const float* g1_b    = (const float*)d_in[16];
  const float* g2_W    = (const float*)d_in[17];
  const float* g2_b    = (const float*)d_in[18];
  float* out = (float*)d_out;

  char* ws = (char*)d_ws;
  size_t off = 0;
  auto alloc = [&](size_t bytes) -> void* {
    void* p = ws + off;
    off = (off + bytes + 255) & ~(size_t)255;
    return p;
  };
  unsigned long long* packed = (unsigned long long*)alloc((size_t)kN * 64 * 8);
  _Float16* x1b  = (_Float16*)alloc((size_t)kN * 96 * 2);
  _Float16* x2b  = (_Float16*)alloc((size_t)kN * 96 * 2);
  _Float16* Ht   = (_Float16*)alloc((size_t)kH * 68 * kN * 2);
  _Float16* Hto  = (_Float16*)alloc((size_t)68 * kN * 2);
  _Float16* hcatb= (_Float16*)alloc((size_t)kN * 288 * 2);
  _Float16* gb   = (_Float16*)alloc((size_t)kN * 96 * 2);
  _Float16* g2bv = (_Float16*)alloc((size_t)kN * 96 * 2);
  float* f1   = (float*)alloc((size_t)kH * kN * 4);
  float* f2   = (float*)alloc((size_t)kH * kN * 4);
  float* fo1  = (float*)alloc((size_t)kN * 4);
  float* fo2  = (float*)alloc((size_t)kN * 4);
  unsigned int* fmaxbuf = (unsigned int*)alloc(64);
  float* u    = (float*)alloc((size_t)kN * kU * 4);
  _Float16* paccb = (_Float16*)alloc((size_t)16 * kN * 80 * 2);
  _Float16* B1t  = (_Float16*)alloc((size_t)kH * 80 * 96 * 2);
  _Float16* B1t2 = (_Float16*)alloc((size_t)kH * 80 * 96 * 2);
  _Float16* B2t  = (_Float16*)alloc((size_t)80 * 288 * 2);
  _Float16* B2t2 = (_Float16*)alloc((size_t)80 * 288 * 2);
  _Float16* Bgt  = (_Float16*)alloc((size_t)128 * 96 * 2);
  _Float16* Bft  = (_Float16*)alloc((size_t)64 * 96 * 2);
  (void)ws_size; (void)in_sizes; (void)n_in; (void)out_size;

  setup_k<<<16384 + 1024 + 12, 256, 0, stream>>>(adj, packed, inputs, hx, x1b, x2b,
      m1_W, m1_a1, m1_a2, m1_Wout, m1_ao1, m1_ao2,
      m2_W, m2_a1, m2_a2, m2_Wout, m2_ao1, m2_ao2,
      g1_W, g1_b, g2_W, g2_b,
      B1t, B1t2, B2t, B2t2, Bgt, Bft, fmaxbuf);

  // ---- subnet 1 ----
  gemm_k<3, 5, 0><<<dim3(64, kH), 256, 0, stream>>>(x1b, B1t, Ht, f1, f2, nullptr, fmaxbuf + 0);
  attn_mfma_k<4><<<dim3(64, kH, 4), 256, 0, stream>>>(Ht, f1, f2, fmaxbuf + 0, packed, paccb);
  combine_k<4><<<dim3(64, kH), 256, 0, stream>>>(paccb, hcatb, 288, 72, 0);
  gemm_k<9, 5, 0><<<dim3(64, 1), 256, 0, stream>>>(hcatb, B2t, Hto, fo1, fo2, nullptr, fmaxbuf + 4);
  attn_mfma_k<8><<<dim3(64, 1, 8), 256, 0, stream>>>(Hto, fo1, fo2, fmaxbuf + 4, packed, paccb);
  combine_k<8><<<dim3(64, 1), 256, 0, stream>>>(paccb, gb, 96, 0, 1);
  gemm_k<3, 8, 1><<<dim3(64, 1), 256, 0, stream>>>(gb, Bgt, u, x2b, nullptr, hx, nullptr);

  // ---- subnet 2 ----
  gemm_k<3, 5, 0><<<dim3(64, kH), 256, 0, stream>>>(x2b, B1t2, Ht, f1, f2, nullptr, fmaxbuf + 5);
  attn_mfma_k<4><<<dim3(64, kH, 4), 256, 0, stream>>>(Ht, f1, f2, fmaxbuf + 5, packed, paccb);
  combine_k<4><<<dim3(64, kH), 256, 0, stream>>>(paccb, hcatb, 288, 72, 0);
  gemm_k<9, 5, 0><<<dim3(64, 1), 256, 0, stream>>>(hcatb, B2t2, Hto, fo1, fo2, nullptr, fmaxbuf + 9);
  attn_mfma_k<8><<<dim3(64, 1, 8), 256, 0, stream>>>(Hto, fo1, fo2, fmaxbuf + 9, packed, paccb);
  combine_k<8><<<dim3(64, 1), 256, 0, stream>>>(paccb, g2bv, 96, 0, 1);
  gemm_k<3, 4, 2><<<dim3(64, 1), 256, 0, stream>>>(g2bv, Bft, out, u, nullptr, hx, nullptr);
}